// Round 7
// baseline (290.870 us; speedup 1.0000x reference)
//
#include <hip/hip_runtime.h>
#include <hip/hip_bf16.h>
#include <math.h>

#define DIM    384
#define NHEAD  8
#define HDIM   48
#define NTOK   2048              // tokens per batch (8*16*16)
#define BATCH  2
#define TOKS   (BATCH * NTOK)    // 4096
#define HIDDEN 1536

typedef __bf16 bf16x8 __attribute__((ext_vector_type(8)));
typedef float  f32x4  __attribute__((ext_vector_type(4)));
typedef unsigned short u16;

__device__ __forceinline__ void load_lds16(const void* g, void* l) {
    __builtin_amdgcn_global_load_lds(
        (const __attribute__((address_space(1))) void*)g,
        (__attribute__((address_space(3))) void*)l, 16, 0, 0);
}

// ---------------------------------------------------------------------------
// All four weight cast+transposes in ONE dispatch.
// in f32 [R][C] -> out bf16 [C][R]; block ranges select the matrix.
// tiles: Wqkv 432, Wo 144, W1 576, W2 576  (total 1728)
// ---------------------------------------------------------------------------
__global__ __launch_bounds__(256) void wtrans_all(
    const float* __restrict__ Wqkv, const float* __restrict__ Wo,
    const float* __restrict__ W1,   const float* __restrict__ W2,
    __hip_bfloat16* __restrict__ WqkvT, __hip_bfloat16* __restrict__ WoT,
    __hip_bfloat16* __restrict__ W1T,   __hip_bfloat16* __restrict__ W2T) {
    __shared__ float t[32][33];
    int id = blockIdx.x;
    const float* src; __hip_bfloat16* dst; int R, C;
    if (id < 432)       { src = Wqkv; dst = WqkvT; R = 384;  C = 1152; }
    else if (id < 576)  { id -= 432;  src = Wo;    dst = WoT;  R = 384;  C = 384; }
    else if (id < 1152) { id -= 576;  src = W1;    dst = W1T;  R = 384;  C = 1536; }
    else                { id -= 1152; src = W2;    dst = W2T;  R = 1536; C = 384; }
    int tc = C / 32;
    int i0 = (id / tc) * 32, j0 = (id % tc) * 32;
    int tx = threadIdx.x & 31, ty = threadIdx.x >> 5;
#pragma unroll
    for (int k = 0; k < 32; k += 8)
        t[ty + k][tx] = src[(size_t)(i0 + ty + k) * C + j0 + tx];
    __syncthreads();
#pragma unroll
    for (int k = 0; k < 32; k += 8)
        dst[(size_t)(j0 + ty + k) * R + i0 + tx] = __float2bfloat16(t[tx][ty + k]);
}

// ---------------------------------------------------------------------------
// Fused input transpose + LN1.
// x f32 [B][C=384][N=2048] -> h f32 [tok][384] (residual) + LN bf16 [tok][384].
// ---------------------------------------------------------------------------
__global__ __launch_bounds__(256) void tln(const float* __restrict__ x,
                                           const float* __restrict__ g,
                                           const float* __restrict__ bta,
                                           float* __restrict__ hOut,
                                           __hip_bfloat16* __restrict__ y) {
    __shared__ float t[384 * 33];
    int n0 = blockIdx.x * 32, b = blockIdx.y;
    const float* xb = x + (size_t)b * DIM * NTOK;
    int tid = threadIdx.x;
    for (int idx = tid; idx < 384 * 32; idx += 256) {
        int c = idx >> 5, n = idx & 31;
        t[c * 33 + n] = xb[(size_t)c * NTOK + n0 + n];
    }
    __syncthreads();
    int wid = tid >> 6, lane = tid & 63;
#pragma unroll
    for (int it = 0; it < 8; ++it) {
        int tl = it * 4 + wid;                 // token local 0..31
        float v[6];
        float s = 0.f;
#pragma unroll
        for (int i = 0; i < 6; ++i) { v[i] = t[(lane + 64 * i) * 33 + tl]; s += v[i]; }
#pragma unroll
        for (int o = 32; o; o >>= 1) s += __shfl_xor(s, o, 64);
        float mu = s * (1.f / DIM);
        float s2 = 0.f;
#pragma unroll
        for (int i = 0; i < 6; ++i) { float d = v[i] - mu; s2 += d * d; }
#pragma unroll
        for (int o = 32; o; o >>= 1) s2 += __shfl_xor(s2, o, 64);
        float r = rsqrtf(s2 * (1.f / DIM) + 1e-6f);
        size_t tok = (size_t)b * NTOK + n0 + tl;
#pragma unroll
        for (int i = 0; i < 6; ++i) {
            int c = lane + 64 * i;
            hOut[tok * DIM + c] = v[i];
            y[tok * DIM + c] = __float2bfloat16((v[i] - mu) * r * g[c] + bta[c]);
        }
    }
}

// ---------------------------------------------------------------------------
// V transpose: qkv bf16 [tok][1152] (V cols 768+h*48+d) -> VT [b*8+h][48][2048]
// ---------------------------------------------------------------------------
__global__ __launch_bounds__(256) void vtile(const u16* __restrict__ qkv,
                                             u16* __restrict__ vt) {
    __shared__ u16 t[32][17];
    int k0 = blockIdx.x * 32;
    int d0 = blockIdx.y * 16;
    int bh = blockIdx.z;
    int b = bh >> 3, h = bh & 7;
    int tid = threadIdx.x;
#pragma unroll
    for (int idx = tid; idx < 512; idx += 256) {
        int key = idx >> 4, d = idx & 15;
        t[key][d] = qkv[(size_t)(b * NTOK + k0 + key) * 1152 + 768 + h * 48 + d0 + d];
    }
    __syncthreads();
#pragma unroll
    for (int idx = tid; idx < 512; idx += 256) {
        int d = idx >> 5, key = idx & 31;
        vt[((size_t)bh * 48 + d0 + d) * 2048 + k0 + key] = t[key][d];
    }
}

// ---------------------------------------------------------------------------
// LayerNorm (LN2): one wave per token, 4 tokens/block. f32 in, bf16 out.
// ---------------------------------------------------------------------------
__global__ __launch_bounds__(256) void ln_kernel(const float* __restrict__ x,
                                                 const float* __restrict__ g,
                                                 const float* __restrict__ bta,
                                                 __hip_bfloat16* __restrict__ y) {
    int wid = threadIdx.x >> 6, lane = threadIdx.x & 63;
    int tok = blockIdx.x * 4 + wid;
    const float* xr = x + (size_t)tok * DIM;
    float v[6];
    float s = 0.f;
#pragma unroll
    for (int i = 0; i < 6; ++i) { v[i] = xr[lane + 64 * i]; s += v[i]; }
#pragma unroll
    for (int o = 32; o; o >>= 1) s += __shfl_xor(s, o, 64);
    float mu = s * (1.f / DIM);
    float s2 = 0.f;
#pragma unroll
    for (int i = 0; i < 6; ++i) { float d = v[i] - mu; s2 += d * d; }
#pragma unroll
    for (int o = 32; o; o >>= 1) s2 += __shfl_xor(s2, o, 64);
    float r = rsqrtf(s2 * (1.f / DIM) + 1e-6f);
    __hip_bfloat16* yr = y + (size_t)tok * DIM;
#pragma unroll
    for (int i = 0; i < 6; ++i) {
        int c = lane + 64 * i;
        yr[c] = __float2bfloat16((v[i] - mu) * r * g[c] + bta[c]);
    }
}

// ---------------------------------------------------------------------------
// 64x64x32 bf16 MFMA GEMM: C = epi(A @ BT^T + bias) (+res)
// TRANSOUT: write f32 out[b][c][n] transposed via LDS tile (N must be 384).
// ---------------------------------------------------------------------------
template<bool GELU, bool BF16OUT, bool TRANSOUT>
__global__ __launch_bounds__(256) void gemm_mfma(
    const __hip_bfloat16* __restrict__ A,    // [M,K]
    const __hip_bfloat16* __restrict__ BT,   // [N,K]
    const float* __restrict__ bias,
    const float* __restrict__ res,
    void* __restrict__ Cout,
    int M, int N, int K) {
    __shared__ __align__(16) u16 As[64 * 32];
    __shared__ __align__(16) u16 Bs[64 * 32];
    int bm = blockIdx.y * 64, bn = blockIdx.x * 64;
    int tid = threadIdx.x;
    int w = tid >> 6, l = tid & 63;
    int m0 = (w >> 1) * 32, n0 = (w & 1) * 32;
    int lm = l & 15, ksel = l >> 4;

    int row = tid >> 2, c16 = tid & 3;
    const __hip_bfloat16* ga = A  + (size_t)(bm + row) * K + c16 * 8;
    const __hip_bfloat16* gb = BT + (size_t)(bn + row) * K + c16 * 8;
    u16* la = &As[tid * 8];
    u16* lb = &Bs[tid * 8];

    f32x4 acc[2][2] = {};
    for (int k0 = 0; k0 < K; k0 += 32) {
        load_lds16(ga + k0, la);
        load_lds16(gb + k0, lb);
        __syncthreads();
        bf16x8 af0 = *(const bf16x8*)&As[(m0 +      lm) * 32 + ksel * 8];
        bf16x8 af1 = *(const bf16x8*)&As[(m0 + 16 + lm) * 32 + ksel * 8];
        bf16x8 bf0 = *(const bf16x8*)&Bs[(n0 +      lm) * 32 + ksel * 8];
        bf16x8 bf1 = *(const bf16x8*)&Bs[(n0 + 16 + lm) * 32 + ksel * 8];
        acc[0][0] = __builtin_amdgcn_mfma_f32_16x16x32_bf16(af0, bf0, acc[0][0], 0, 0, 0);
        acc[0][1] = __builtin_amdgcn_mfma_f32_16x16x32_bf16(af0, bf1, acc[0][1], 0, 0, 0);
        acc[1][0] = __builtin_amdgcn_mfma_f32_16x16x32_bf16(af1, bf0, acc[1][0], 0, 0, 0);
        acc[1][1] = __builtin_amdgcn_mfma_f32_16x16x32_bf16(af1, bf1, acc[1][1], 0, 0, 0);
        __syncthreads();
    }

    if constexpr (TRANSOUT) {
        __shared__ float ct[64 * 65];
#pragma unroll
        for (int i = 0; i < 2; ++i)
#pragma unroll
            for (int j = 0; j < 2; ++j)
#pragma unroll
                for (int r = 0; r < 4; ++r) {
                    int ml = m0 + i * 16 + ksel * 4 + r;
                    int cl = n0 + j * 16 + lm;
                    float v = acc[i][j][r];
                    if (bias) v += bias[bn + cl];
                    if (res)  v += res[(size_t)(bm + ml) * N + bn + cl];
                    ct[ml * 65 + cl] = v;
                }
        __syncthreads();
        int bb = bm >> 11, nb = bm & (NTOK - 1);
        float* outp = (float*)Cout + (size_t)bb * DIM * NTOK + nb;
#pragma unroll
        for (int cl = w; cl < 64; cl += 4)
            outp[(size_t)(bn + cl) * NTOK + l] = ct[l * 65 + cl];
    } else {
#pragma unroll
        for (int i = 0; i < 2; ++i)
#pragma unroll
            for (int j = 0; j < 2; ++j)
#pragma unroll
                for (int r = 0; r < 4; ++r) {
                    int rg = bm + m0 + i * 16 + ksel * 4 + r;
                    int cg = bn + n0 + j * 16 + lm;
                    float v = acc[i][j][r];
                    if (bias) v += bias[cg];
                    if (GELU) v = 0.5f * v * (1.f + erff(v * 0.7071067811865475f));
                    if (res)  v += res[(size_t)rg * N + cg];
                    if (BF16OUT)
                        ((__hip_bfloat16*)Cout)[(size_t)rg * N + cg] = __float2bfloat16(v);
                    else
                        ((float*)Cout)[(size_t)rg * N + cg] = v;
                }
    }
}

// ---------------------------------------------------------------------------
// bf16 MFMA flash attention, 128-key tiles, one-pass softmax, BARRIER-FREE
// K-loop: K fragments are loaded directly from global qkv (the k-dim pad
// 48..63 reads the next head's finite data, which is multiplied by Q's LDS
// zero-pad -> contributes 0), V fragments directly from global VT. Only Q
// (staged once) and the wave-private P round-trip use LDS.
// Grid (NTOK/64, NHEAD, BATCH), 256 threads = 4 waves; wave w owns q rows
// w*16..w*16+15.
// ---------------------------------------------------------------------------
#define ATK 128
#define PSTR 134   // odd word stride (67 words): conflict-free pf b128 reads
__global__ __launch_bounds__(256) void attn_mfma(
    const u16* __restrict__ qkv,             // bf16 [TOKS][1152]
    const u16* __restrict__ vt,              // bf16 [16][48][2048]
    __hip_bfloat16* __restrict__ outp) {     // bf16 [TOKS][DIM]
    __shared__ __align__(16) u16 Qs[64 * 72];
    __shared__ __align__(16) __hip_bfloat16 Ps[64 * PSTR];
    const int q0 = blockIdx.x * 64;
    const int h = blockIdx.y, b = blockIdx.z;
    const int tid = threadIdx.x;
    const int w = tid >> 6, l = tid & 63, lm = l & 15, quad = l >> 4;

    // zero the k-pad (cols 48..63) of Qs
    for (int idx = tid; idx < 128; idx += 256) {
        int r = idx >> 1, c = idx & 1;
        *(uint4*)&Qs[r * 72 + 48 + c * 8] = uint4{0, 0, 0, 0};
    }
    // stage Q tile (64 rows x 48)
    const u16* qbase = qkv + (size_t)(b * NTOK + q0) * 1152 + h * 48;
    for (int idx = tid; idx < 384; idx += 256) {
        int r = idx / 6, c = idx % 6;
        *(uint4*)&Qs[r * 72 + c * 8] = *(const uint4*)(qbase + (size_t)r * 1152 + c * 8);
    }
    __syncthreads();

    bf16x8 aq0 = *(const bf16x8*)&Qs[(w * 16 + lm) * 72 +  0 + quad * 8];
    bf16x8 aq1 = *(const bf16x8*)&Qs[(w * 16 + lm) * 72 + 32 + quad * 8];

    float l_i[4] = {0.f, 0.f, 0.f, 0.f};
    f32x4 o_acc[3] = {};

    // K fragment base: row (kt*128 + nt*16 + lm), k-chunk quad*8 (+32 for kf1)
    const u16* kfrag = qkv + (size_t)(b * NTOK) * 1152 + 384 + h * 48
                     + (size_t)lm * 1152 + quad * 8;
    // V fragment base: d-row (nt*16 + lm), key-chunk ks*32 + quad*8
    const u16* vfrag = vt + (size_t)(b * NHEAD + h) * 48 * 2048
                     + (size_t)lm * 2048 + quad * 8;
    const float sc2 = 0.14433756729740643f * 1.4426950408889634f;  // scale*log2e

    for (int kt = 0; kt < NTOK / ATK; ++kt) {
        // S = Q K^T : 8 key-subtiles of 16, K straight from global
        f32x4 s[8];
#pragma unroll
        for (int nt = 0; nt < 8; ++nt) {
            const u16* kr = kfrag + (size_t)(kt * ATK + nt * 16) * 1152;
            bf16x8 kf0 = *(const bf16x8*)(kr);
            bf16x8 kf1 = *(const bf16x8*)(kr + 32);
            f32x4 t = {};
            t = __builtin_amdgcn_mfma_f32_16x16x32_bf16(aq0, kf0, t, 0, 0, 0);
            t = __builtin_amdgcn_mfma_f32_16x16x32_bf16(aq1, kf1, t, 0, 0, 0);
            s[nt] = t;
        }

        // P = exp2(S*sc2); per-lane partial l; store P (wave-private rows)
#pragma unroll
        for (int r = 0; r < 4; ++r) {
#pragma unroll
            for (int nt = 0; nt < 8; ++nt) {
                float p = exp2f(s[nt][r] * sc2);
                l_i[r] += p;
                Ps[(w * 16 + quad * 4 + r) * PSTR + nt * 16 + lm] = __float2bfloat16(p);
            }
        }

        // O += P V : P from wave-private LDS, V straight from global VT
#pragma unroll
        for (int ks = 0; ks < 4; ++ks) {
            bf16x8 pf = *(const bf16x8*)&Ps[(w * 16 + lm) * PSTR + ks * 32 + quad * 8];
#pragma unroll
            for (int nt = 0; nt < 3; ++nt) {
                bf16x8 vf = *(const bf16x8*)(vfrag + (size_t)(nt * 16) * 2048
                                             + kt * ATK + ks * 32);
                o_acc[nt] = __builtin_amdgcn_mfma_f32_16x16x32_bf16(pf, vf, o_acc[nt], 0, 0, 0);
            }
        }
    }

#pragma unroll
    for (int r = 0; r < 4; ++r) {
        float lsum = l_i[r];
#pragma unroll
        for (int o = 8; o; o >>= 1) lsum += __shfl_xor(lsum, o, 64);
        float inv = 1.f / lsum;
#pragma unroll
        for (int nt = 0; nt < 3; ++nt)
            outp[(size_t)(b * NTOK + q0 + w * 16 + quad * 4 + r) * DIM + h * 48 + nt * 16 + lm]
                = __float2bfloat16(o_acc[nt][r] * inv);
    }
}

// ---------------------------------------------------------------------------
extern "C" void kernel_launch(void* const* d_in, const int* in_sizes, int n_in,
                              void* d_out, int out_size, void* d_ws, size_t ws_size,
                              hipStream_t stream) {
    const float* x    = (const float*)d_in[0];
    const float* g1   = (const float*)d_in[1];
    const float* b1   = (const float*)d_in[2];
    const float* Wqkv = (const float*)d_in[3];
    const float* Wo   = (const float*)d_in[4];
    const float* bo   = (const float*)d_in[5];
    const float* g2   = (const float*)d_in[6];
    const float* b2   = (const float*)d_in[7];
    const float* W1   = (const float*)d_in[8];
    const float* b1m  = (const float*)d_in[9];
    const float* W2   = (const float*)d_in[10];
    const float* b2m  = (const float*)d_in[11];
    float* out = (float*)d_out;

    char* p = (char*)d_ws;
    float* bufH = (float*)p;                       p += (size_t)TOKS * DIM * 4;      // f32 [4096,384]
    char* qkvp = p;
    __hip_bfloat16* bufQKVb = (__hip_bfloat16*)p;  p += (size_t)TOKS * 3 * DIM * 2;  // bf16 [4096,1152]
    __hip_bfloat16* bufVT   = (__hip_bfloat16*)p;  p += (size_t)TOKS * DIM * 2;      // bf16 [16,48,2048]
    __hip_bfloat16* bufNb   = (__hip_bfloat16*)p;  p += (size_t)TOKS * DIM * 2;      // bf16 [4096,384]
    __hip_bfloat16* bufAb   = (__hip_bfloat16*)p;  p += (size_t)TOKS * DIM * 2;      // bf16 [4096,384]
    __hip_bfloat16* WqkvT   = (__hip_bfloat16*)p;  p += (size_t)3 * DIM * DIM * 2;   // [1152,384]
    __hip_bfloat16* WoT     = (__hip_bfloat16*)p;  p += (size_t)DIM * DIM * 2;       // [384,384]
    __hip_bfloat16* W1T     = (__hip_bfloat16*)p;  p += (size_t)HIDDEN * DIM * 2;    // [1536,384]
    __hip_bfloat16* W2T     = (__hip_bfloat16*)p;  p += (size_t)DIM * HIDDEN * 2;    // [384,1536]
    __hip_bfloat16* bufHIDb = (__hip_bfloat16*)qkvp;  // bf16 [4096,1536] overlays QKV+VT

    // 0. all weight casts/transposes (one dispatch)
    wtrans_all<<<1728, 256, 0, stream>>>(Wqkv, Wo, W1, W2, WqkvT, WoT, W1T, W2T);
    // 1. fused transpose + LN1: x -> bufH (f32 h) + bufNb (bf16 LN)
    tln<<<dim3(NTOK / 32, BATCH), 256, 0, stream>>>(x, g1, b1, bufH, bufNb);
    // 2. QKV projection -> bf16
    gemm_mfma<false, true, false><<<dim3(3 * DIM / 64, TOKS / 64), 256, 0, stream>>>(
        bufNb, WqkvT, nullptr, nullptr, bufQKVb, TOKS, 3 * DIM, DIM);
    // 3. V transpose
    vtile<<<dim3(NTOK / 32, HDIM / 16, BATCH * NHEAD), 256, 0, stream>>>(
        (const u16*)bufQKVb, (u16*)bufVT);
    // 4. MFMA flash attention -> bf16
    attn_mfma<<<dim3(NTOK / 64, NHEAD, BATCH), 256, 0, stream>>>(
        (const u16*)bufQKVb, (const u16*)bufVT, bufAb);
    // 5. output projection + bias + residual -> f32 bufH (in place)
    gemm_mfma<false, false, false><<<dim3(DIM / 64, TOKS / 64), 256, 0, stream>>>(
        bufAb, WoT, bo, bufH, bufH, TOKS, DIM, DIM);
    // 6. LN2 -> bf16
    ln_kernel<<<TOKS / 4, 256, 0, stream>>>(bufH, g2, b2, bufNb);
    // 7. MLP up + GELU -> bf16 hidden
    gemm_mfma<true, true, false><<<dim3(HIDDEN / 64, TOKS / 64), 256, 0, stream>>>(
        bufNb, W1T, b1m, nullptr, bufHIDb, TOKS, HIDDEN, DIM);
    // 8. MLP down + bias + residual -> out (transposed write, f32)
    gemm_mfma<false, false, true><<<dim3(DIM / 64, TOKS / 64), 256, 0, stream>>>(
        bufHIDb, W2T, b2m, bufH, out, TOKS, DIM, HIDDEN);
}

// Round 8
// 244.702 us; speedup vs baseline: 1.1887x; 1.1887x over previous
//
#include <hip/hip_runtime.h>
#include <hip/hip_bf16.h>
#include <math.h>

#define DIM    384
#define NHEAD  8
#define HDIM   48
#define NTOK   2048              // tokens per batch (8*16*16)
#define BATCH  2
#define TOKS   (BATCH * NTOK)    // 4096
#define HIDDEN 1536

typedef __bf16 bf16x8 __attribute__((ext_vector_type(8)));
typedef float  f32x4  __attribute__((ext_vector_type(4)));
typedef unsigned short u16;

__device__ __forceinline__ void load_lds16(const void* g, void* l) {
    __builtin_amdgcn_global_load_lds(
        (const __attribute__((address_space(1))) void*)g,
        (__attribute__((address_space(3))) void*)l, 16, 0, 0);
}

// ---------------------------------------------------------------------------
// All four weight cast+transposes in ONE dispatch.
// in f32 [R][C] -> out bf16 [C][R]; block ranges select the matrix.
// ---------------------------------------------------------------------------
__global__ __launch_bounds__(256) void wtrans_all(
    const float* __restrict__ Wqkv, const float* __restrict__ Wo,
    const float* __restrict__ W1,   const float* __restrict__ W2,
    __hip_bfloat16* __restrict__ WqkvT, __hip_bfloat16* __restrict__ WoT,
    __hip_bfloat16* __restrict__ W1T,   __hip_bfloat16* __restrict__ W2T) {
    __shared__ float t[32][33];
    int id = blockIdx.x;
    const float* src; __hip_bfloat16* dst; int R, C;
    if (id < 432)       { src = Wqkv; dst = WqkvT; R = 384;  C = 1152; }
    else if (id < 576)  { id -= 432;  src = Wo;    dst = WoT;  R = 384;  C = 384; }
    else if (id < 1152) { id -= 576;  src = W1;    dst = W1T;  R = 384;  C = 1536; }
    else                { id -= 1152; src = W2;    dst = W2T;  R = 1536; C = 384; }
    int tc = C / 32;
    int i0 = (id / tc) * 32, j0 = (id % tc) * 32;
    int tx = threadIdx.x & 31, ty = threadIdx.x >> 5;
#pragma unroll
    for (int k = 0; k < 32; k += 8)
        t[ty + k][tx] = src[(size_t)(i0 + ty + k) * C + j0 + tx];
    __syncthreads();
#pragma unroll
    for (int k = 0; k < 32; k += 8)
        dst[(size_t)(j0 + ty + k) * R + i0 + tx] = __float2bfloat16(t[tx][ty + k]);
}

// ---------------------------------------------------------------------------
// Fused input transpose + LN1.
// ---------------------------------------------------------------------------
__global__ __launch_bounds__(256) void tln(const float* __restrict__ x,
                                           const float* __restrict__ g,
                                           const float* __restrict__ bta,
                                           float* __restrict__ hOut,
                                           __hip_bfloat16* __restrict__ y) {
    __shared__ float t[384 * 33];
    int n0 = blockIdx.x * 32, b = blockIdx.y;
    const float* xb = x + (size_t)b * DIM * NTOK;
    int tid = threadIdx.x;
    for (int idx = tid; idx < 384 * 32; idx += 256) {
        int c = idx >> 5, n = idx & 31;
        t[c * 33 + n] = xb[(size_t)c * NTOK + n0 + n];
    }
    __syncthreads();
    int wid = tid >> 6, lane = tid & 63;
#pragma unroll
    for (int it = 0; it < 8; ++it) {
        int tl = it * 4 + wid;
        float v[6];
        float s = 0.f;
#pragma unroll
        for (int i = 0; i < 6; ++i) { v[i] = t[(lane + 64 * i) * 33 + tl]; s += v[i]; }
#pragma unroll
        for (int o = 32; o; o >>= 1) s += __shfl_xor(s, o, 64);
        float mu = s * (1.f / DIM);
        float s2 = 0.f;
#pragma unroll
        for (int i = 0; i < 6; ++i) { float d = v[i] - mu; s2 += d * d; }
#pragma unroll
        for (int o = 32; o; o >>= 1) s2 += __shfl_xor(s2, o, 64);
        float r = rsqrtf(s2 * (1.f / DIM) + 1e-6f);
        size_t tok = (size_t)b * NTOK + n0 + tl;
#pragma unroll
        for (int i = 0; i < 6; ++i) {
            int c = lane + 64 * i;
            hOut[tok * DIM + c] = v[i];
            y[tok * DIM + c] = __float2bfloat16((v[i] - mu) * r * g[c] + bta[c]);
        }
    }
}

// ---------------------------------------------------------------------------
// V transpose: qkv bf16 [tok][1152] (V cols 768+h*48+d) -> VT [b*8+h][48][2048]
// ---------------------------------------------------------------------------
__global__ __launch_bounds__(256) void vtile(const u16* __restrict__ qkv,
                                             u16* __restrict__ vt) {
    __shared__ u16 t[32][17];
    int k0 = blockIdx.x * 32;
    int d0 = blockIdx.y * 16;
    int bh = blockIdx.z;
    int b = bh >> 3, h = bh & 7;
    int tid = threadIdx.x;
#pragma unroll
    for (int idx = tid; idx < 512; idx += 256) {
        int key = idx >> 4, d = idx & 15;
        t[key][d] = qkv[(size_t)(b * NTOK + k0 + key) * 1152 + 768 + h * 48 + d0 + d];
    }
    __syncthreads();
#pragma unroll
    for (int idx = tid; idx < 512; idx += 256) {
        int d = idx >> 5, key = idx & 31;
        vt[((size_t)bh * 48 + d0 + d) * 2048 + k0 + key] = t[key][d];
    }
}

// ---------------------------------------------------------------------------
// LayerNorm (LN2): one wave per token, 4 tokens/block. f32 in, bf16 out.
// ---------------------------------------------------------------------------
__global__ __launch_bounds__(256) void ln_kernel(const float* __restrict__ x,
                                                 const float* __restrict__ g,
                                                 const float* __restrict__ bta,
                                                 __hip_bfloat16* __restrict__ y) {
    int wid = threadIdx.x >> 6, lane = threadIdx.x & 63;
    int tok = blockIdx.x * 4 + wid;
    const float* xr = x + (size_t)tok * DIM;
    float v[6];
    float s = 0.f;
#pragma unroll
    for (int i = 0; i < 6; ++i) { v[i] = xr[lane + 64 * i]; s += v[i]; }
#pragma unroll
    for (int o = 32; o; o >>= 1) s += __shfl_xor(s, o, 64);
    float mu = s * (1.f / DIM);
    float s2 = 0.f;
#pragma unroll
    for (int i = 0; i < 6; ++i) { float d = v[i] - mu; s2 += d * d; }
#pragma unroll
    for (int o = 32; o; o >>= 1) s2 += __shfl_xor(s2, o, 64);
    float r = rsqrtf(s2 * (1.f / DIM) + 1e-6f);
    __hip_bfloat16* yr = y + (size_t)tok * DIM;
#pragma unroll
    for (int i = 0; i < 6; ++i) {
        int c = lane + 64 * i;
        yr[c] = __float2bfloat16((v[i] - mu) * r * g[c] + bta[c]);
    }
}

// ---------------------------------------------------------------------------
// 128x64x32 bf16 MFMA GEMM: C = epi(A @ BT^T + bias) (+res)
// 4 waves 2x2; wave owns 64x32 out (4x2 of 16x16x32): 6 ds_read : 8 MFMA.
// TRANSOUT: write f32 out[b][c][n] transposed via LDS tile (N must be 384).
// ---------------------------------------------------------------------------
template<bool GELU, bool BF16OUT, bool TRANSOUT>
__global__ __launch_bounds__(256) void gemm_mfma(
    const __hip_bfloat16* __restrict__ A,    // [M,K]
    const __hip_bfloat16* __restrict__ BT,   // [N,K]
    const float* __restrict__ bias,
    const float* __restrict__ res,
    void* __restrict__ Cout,
    int M, int N, int K) {
    __shared__ __align__(16) u16 As[128 * 32];
    __shared__ __align__(16) u16 Bs[64 * 32];
    int bm = blockIdx.y * 128, bn = blockIdx.x * 64;
    int tid = threadIdx.x;
    int w = tid >> 6, l = tid & 63;
    int wm = (w >> 1) * 64, wn = (w & 1) * 32;
    int lm = l & 15, quad = l >> 4;

    // staging: A = 512 chunks (2 insts), B = 256 chunks (1 inst)
    int r0 = tid >> 2, c0 = (tid & 3) * 8;
    int r1 = (tid + 256) >> 2, c1 = ((tid + 256) & 3) * 8;
    const __hip_bfloat16* ga0 = A  + (size_t)(bm + r0) * K + c0;
    const __hip_bfloat16* ga1 = A  + (size_t)(bm + r1) * K + c1;
    const __hip_bfloat16* gb  = BT + (size_t)(bn + r0) * K + c0;
    u16* la0 = &As[tid * 8];
    u16* la1 = &As[(tid + 256) * 8];
    u16* lb  = &Bs[tid * 8];

    f32x4 acc[4][2] = {};
    for (int k0 = 0; k0 < K; k0 += 32) {
        load_lds16(ga0 + k0, la0);
        load_lds16(ga1 + k0, la1);
        load_lds16(gb + k0, lb);
        __syncthreads();
        bf16x8 af[4], bf[2];
#pragma unroll
        for (int i = 0; i < 4; ++i)
            af[i] = *(const bf16x8*)&As[(wm + i * 16 + lm) * 32 + quad * 8];
#pragma unroll
        for (int j = 0; j < 2; ++j)
            bf[j] = *(const bf16x8*)&Bs[(wn + j * 16 + lm) * 32 + quad * 8];
#pragma unroll
        for (int i = 0; i < 4; ++i)
#pragma unroll
            for (int j = 0; j < 2; ++j)
                acc[i][j] = __builtin_amdgcn_mfma_f32_16x16x32_bf16(af[i], bf[j], acc[i][j], 0, 0, 0);
        __syncthreads();
    }

    if constexpr (TRANSOUT) {
        __shared__ float ct[128 * 65];
#pragma unroll
        for (int i = 0; i < 4; ++i)
#pragma unroll
            for (int j = 0; j < 2; ++j)
#pragma unroll
                for (int r = 0; r < 4; ++r) {
                    int ml = wm + i * 16 + quad * 4 + r;
                    int cl = wn + j * 16 + lm;
                    float v = acc[i][j][r];
                    if (bias) v += bias[bn + cl];
                    if (res)  v += res[(size_t)(bm + ml) * N + bn + cl];
                    ct[ml * 65 + cl] = v;
                }
        __syncthreads();
        int bb = bm >> 11, nb = bm & (NTOK - 1);
        float* outp = (float*)Cout + (size_t)bb * DIM * NTOK + nb;
#pragma unroll
        for (int cl = w; cl < 64; cl += 4) {
            outp[(size_t)(bn + cl) * NTOK + l]      = ct[l * 65 + cl];
            outp[(size_t)(bn + cl) * NTOK + 64 + l] = ct[(64 + l) * 65 + cl];
        }
    } else {
#pragma unroll
        for (int i = 0; i < 4; ++i)
#pragma unroll
            for (int j = 0; j < 2; ++j)
#pragma unroll
                for (int r = 0; r < 4; ++r) {
                    int rg = bm + wm + i * 16 + quad * 4 + r;
                    int cg = bn + wn + j * 16 + lm;
                    float v = acc[i][j][r];
                    if (bias) v += bias[cg];
                    if (GELU) v = 0.5f * v * (1.f + erff(v * 0.7071067811865475f));
                    if (res)  v += res[(size_t)rg * N + cg];
                    if (BF16OUT)
                        ((__hip_bfloat16*)Cout)[(size_t)rg * N + cg] = __float2bfloat16(v);
                    else
                        ((float*)Cout)[(size_t)rg * N + cg] = v;
                }
    }
}

// ---------------------------------------------------------------------------
// bf16 MFMA flash attention, 128-key tiles, one-pass softmax (round-6 known
// good: LDS-staged K/V, wave-private P round-trip).
// ---------------------------------------------------------------------------
#define ATK 128
__global__ __launch_bounds__(256) void attn_mfma(
    const u16* __restrict__ qkv,             // bf16 [TOKS][1152]
    const u16* __restrict__ vt,              // bf16 [16][48][2048]
    __hip_bfloat16* __restrict__ outp) {     // bf16 [TOKS][DIM]
    __shared__ __align__(16) u16 Qs[64 * 72];
    __shared__ __align__(16) u16 Ks[128 * 72];
    __shared__ __align__(16) u16 Vs[48 * 136];
    __shared__ __align__(16) __hip_bfloat16 Ps[64 * 132];
    const int q0 = blockIdx.x * 64;
    const int h = blockIdx.y, b = blockIdx.z;
    const int tid = threadIdx.x;
    const int w = tid >> 6, l = tid & 63, lm = l & 15, quad = l >> 4;

    for (int idx = tid; idx < 128; idx += 256) {
        int r = idx >> 1, c = idx & 1;
        *(uint4*)&Qs[r * 72 + 48 + c * 8] = uint4{0, 0, 0, 0};
    }
    {
        int r = tid >> 1, c = tid & 1;
        *(uint4*)&Ks[r * 72 + 48 + c * 8] = uint4{0, 0, 0, 0};
    }
    const u16* qbase = qkv + (size_t)(b * NTOK + q0) * 1152 + h * 48;
    for (int idx = tid; idx < 384; idx += 256) {
        int r = idx / 6, c = idx % 6;
        *(uint4*)&Qs[r * 72 + c * 8] = *(const uint4*)(qbase + (size_t)r * 1152 + c * 8);
    }
    __syncthreads();

    bf16x8 aq0 = *(const bf16x8*)&Qs[(w * 16 + lm) * 72 +  0 + quad * 8];
    bf16x8 aq1 = *(const bf16x8*)&Qs[(w * 16 + lm) * 72 + 32 + quad * 8];

    float l_i[4] = {0.f, 0.f, 0.f, 0.f};
    f32x4 o_acc[3] = {};

    const u16* kbase = qkv + (size_t)(b * NTOK) * 1152 + 384 + h * 48;
    const u16* vbase = vt + (size_t)(b * NHEAD + h) * 48 * 2048;
    const float sc2 = 0.14433756729740643f * 1.4426950408889634f;  // scale*log2e

    for (int kt = 0; kt < NTOK / ATK; ++kt) {
        __syncthreads();
#pragma unroll
        for (int idx = tid; idx < 768; idx += 256) {
            int r = idx / 6, c = idx % 6;
            *(uint4*)&Ks[r * 72 + c * 8] =
                *(const uint4*)(kbase + (size_t)(kt * ATK + r) * 1152 + c * 8);
        }
#pragma unroll
        for (int idx = tid; idx < 768; idx += 256) {
            int d = idx >> 4, c = idx & 15;
            *(uint4*)&Vs[d * 136 + c * 8] =
                *(const uint4*)(vbase + (size_t)d * 2048 + kt * ATK + c * 8);
        }
        __syncthreads();

        f32x4 s[8];
#pragma unroll
        for (int nt = 0; nt < 8; ++nt) {
            bf16x8 kf0 = *(const bf16x8*)&Ks[(nt * 16 + lm) * 72 +  0 + quad * 8];
            bf16x8 kf1 = *(const bf16x8*)&Ks[(nt * 16 + lm) * 72 + 32 + quad * 8];
            f32x4 t = {};
            t = __builtin_amdgcn_mfma_f32_16x16x32_bf16(aq0, kf0, t, 0, 0, 0);
            t = __builtin_amdgcn_mfma_f32_16x16x32_bf16(aq1, kf1, t, 0, 0, 0);
            s[nt] = t;
        }

#pragma unroll
        for (int r = 0; r < 4; ++r) {
#pragma unroll
            for (int nt = 0; nt < 8; ++nt) {
                float p = exp2f(s[nt][r] * sc2);
                l_i[r] += p;
                Ps[(w * 16 + quad * 4 + r) * 132 + nt * 16 + lm] = __float2bfloat16(p);
            }
        }

#pragma unroll
        for (int ks = 0; ks < 4; ++ks) {
            bf16x8 pf = *(const bf16x8*)&Ps[(w * 16 + lm) * 132 + ks * 32 + quad * 8];
#pragma unroll
            for (int nt = 0; nt < 3; ++nt) {
                bf16x8 vf = *(const bf16x8*)&Vs[(nt * 16 + lm) * 136 + ks * 32 + quad * 8];
                o_acc[nt] = __builtin_amdgcn_mfma_f32_16x16x32_bf16(pf, vf, o_acc[nt], 0, 0, 0);
            }
        }
    }

#pragma unroll
    for (int r = 0; r < 4; ++r) {
        float lsum = l_i[r];
#pragma unroll
        for (int o = 8; o; o >>= 1) lsum += __shfl_xor(lsum, o, 64);
        float inv = 1.f / lsum;
#pragma unroll
        for (int nt = 0; nt < 3; ++nt)
            outp[(size_t)(b * NTOK + q0 + w * 16 + quad * 4 + r) * DIM + h * 48 + nt * 16 + lm]
                = __float2bfloat16(o_acc[nt][r] * inv);
    }
}

// ---------------------------------------------------------------------------
extern "C" void kernel_launch(void* const* d_in, const int* in_sizes, int n_in,
                              void* d_out, int out_size, void* d_ws, size_t ws_size,
                              hipStream_t stream) {
    const float* x    = (const float*)d_in[0];
    const float* g1   = (const float*)d_in[1];
    const float* b1   = (const float*)d_in[2];
    const float* Wqkv = (const float*)d_in[3];
    const float* Wo   = (const float*)d_in[4];
    const float* bo   = (const float*)d_in[5];
    const float* g2   = (const float*)d_in[6];
    const float* b2   = (const float*)d_in[7];
    const float* W1   = (const float*)d_in[8];
    const float* b1m  = (const float*)d_in[9];
    const float* W2   = (const float*)d_in[10];
    const float* b2m  = (const float*)d_in[11];
    float* out = (float*)d_out;

    char* p = (char*)d_ws;
    float* bufH = (float*)p;                       p += (size_t)TOKS * DIM * 4;      // f32 [4096,384]
    char* qkvp = p;
    __hip_bfloat16* bufQKVb = (__hip_bfloat16*)p;  p += (size_t)TOKS * 3 * DIM * 2;  // bf16 [4096,1152]
    __hip_bfloat16* bufVT   = (__hip_bfloat16*)p;  p += (size_t)TOKS * DIM * 2;      // bf16 [16,48,2048]
    __hip_bfloat16* bufNb   = (__hip_bfloat16*)p;  p += (size_t)TOKS * DIM * 2;      // bf16 [4096,384]
    __hip_bfloat16* bufAb   = (__hip_bfloat16*)p;  p += (size_t)TOKS * DIM * 2;      // bf16 [4096,384]
    __hip_bfloat16* WqkvT   = (__hip_bfloat16*)p;  p += (size_t)3 * DIM * DIM * 2;   // [1152,384]
    __hip_bfloat16* WoT     = (__hip_bfloat16*)p;  p += (size_t)DIM * DIM * 2;       // [384,384]
    __hip_bfloat16* W1T     = (__hip_bfloat16*)p;  p += (size_t)HIDDEN * DIM * 2;    // [1536,384]
    __hip_bfloat16* W2T     = (__hip_bfloat16*)p;  p += (size_t)DIM * HIDDEN * 2;    // [384,1536]
    __hip_bfloat16* bufHIDb = (__hip_bfloat16*)qkvp;  // bf16 [4096,1536] overlays QKV+VT

    // 0. all weight casts/transposes (one dispatch)
    wtrans_all<<<1728, 256, 0, stream>>>(Wqkv, Wo, W1, W2, WqkvT, WoT, W1T, W2T);
    // 1. fused transpose + LN1
    tln<<<dim3(NTOK / 32, BATCH), 256, 0, stream>>>(x, g1, b1, bufH, bufNb);
    // 2. QKV projection -> bf16
    gemm_mfma<false, true, false><<<dim3(3 * DIM / 64, TOKS / 128), 256, 0, stream>>>(
        bufNb, WqkvT, nullptr, nullptr, bufQKVb, TOKS, 3 * DIM, DIM);
    // 3. V transpose
    vtile<<<dim3(NTOK / 32, HDIM / 16, BATCH * NHEAD), 256, 0, stream>>>(
        (const u16*)bufQKVb, (u16*)bufVT);
    // 4. MFMA flash attention -> bf16
    attn_mfma<<<dim3(NTOK / 64, NHEAD, BATCH), 256, 0, stream>>>(
        (const u16*)bufQKVb, (const u16*)bufVT, bufAb);
    // 5. output projection + bias + residual -> f32 bufH (in place)
    gemm_mfma<false, false, false><<<dim3(DIM / 64, TOKS / 128), 256, 0, stream>>>(
        bufAb, WoT, bo, bufH, bufH, TOKS, DIM, DIM);
    // 6. LN2 -> bf16
    ln_kernel<<<TOKS / 4, 256, 0, stream>>>(bufH, g2, b2, bufNb);
    // 7. MLP up + GELU -> bf16 hidden
    gemm_mfma<true, true, false><<<dim3(HIDDEN / 64, TOKS / 128), 256, 0, stream>>>(
        bufNb, W1T, b1m, nullptr, bufHIDb, TOKS, HIDDEN, DIM);
    // 8. MLP down + bias + residual -> out (transposed write, f32)
    gemm_mfma<false, false, true><<<dim3(DIM / 64, TOKS / 128), 256, 0, stream>>>(
        bufHIDb, W2T, b2m, bufH, out, TOKS, DIM, HIDDEN);
}

// Round 10
// 223.403 us; speedup vs baseline: 1.3020x; 1.0953x over previous
//
#include <hip/hip_runtime.h>
#include <hip/hip_bf16.h>
#include <math.h>

#define DIM    384
#define NHEAD  8
#define HDIM   48
#define NTOK   2048              // tokens per batch (8*16*16)
#define BATCH  2
#define TOKS   (BATCH * NTOK)    // 4096
#define HIDDEN 1536

typedef __bf16 bf16x8 __attribute__((ext_vector_type(8)));
typedef float  f32x4  __attribute__((ext_vector_type(4)));
typedef unsigned short u16;

union bfu { __hip_bfloat16 h; u16 u; };

__device__ __forceinline__ void load_lds16(const void* g, void* l) {
    __builtin_amdgcn_global_load_lds(
        (const __attribute__((address_space(1))) void*)g,
        (__attribute__((address_space(3))) void*)l, 16, 0, 0);
}

// ---------------------------------------------------------------------------
// All four weight cast+transposes in ONE dispatch.
// in f32 [R][C] -> out bf16 [C][R]; block ranges select the matrix.
// ---------------------------------------------------------------------------
__global__ __launch_bounds__(256) void wtrans_all(
    const float* __restrict__ Wqkv, const float* __restrict__ Wo,
    const float* __restrict__ W1,   const float* __restrict__ W2,
    __hip_bfloat16* __restrict__ WqkvT, __hip_bfloat16* __restrict__ WoT,
    __hip_bfloat16* __restrict__ W1T,   __hip_bfloat16* __restrict__ W2T) {
    __shared__ float t[32][33];
    int id = blockIdx.x;
    const float* src; __hip_bfloat16* dst; int R, C;
    if (id < 432)       { src = Wqkv; dst = WqkvT; R = 384;  C = 1152; }
    else if (id < 576)  { id -= 432;  src = Wo;    dst = WoT;  R = 384;  C = 384; }
    else if (id < 1152) { id -= 576;  src = W1;    dst = W1T;  R = 384;  C = 1536; }
    else                { id -= 1152; src = W2;    dst = W2T;  R = 1536; C = 384; }
    int tc = C / 32;
    int i0 = (id / tc) * 32, j0 = (id % tc) * 32;
    int tx = threadIdx.x & 31, ty = threadIdx.x >> 5;
#pragma unroll
    for (int k = 0; k < 32; k += 8)
        t[ty + k][tx] = src[(size_t)(i0 + ty + k) * C + j0 + tx];
    __syncthreads();
#pragma unroll
    for (int k = 0; k < 32; k += 8)
        dst[(size_t)(j0 + ty + k) * R + i0 + tx] = __float2bfloat16(t[tx][ty + k]);
}

// ---------------------------------------------------------------------------
// Fused input transpose + LN1.
// ---------------------------------------------------------------------------
__global__ __launch_bounds__(256) void tln(const float* __restrict__ x,
                                           const float* __restrict__ g,
                                           const float* __restrict__ bta,
                                           float* __restrict__ hOut,
                                           __hip_bfloat16* __restrict__ y) {
    __shared__ float t[384 * 33];
    int n0 = blockIdx.x * 32, b = blockIdx.y;
    const float* xb = x + (size_t)b * DIM * NTOK;
    int tid = threadIdx.x;
    for (int idx = tid; idx < 384 * 32; idx += 256) {
        int c = idx >> 5, n = idx & 31;
        t[c * 33 + n] = xb[(size_t)c * NTOK + n0 + n];
    }
    __syncthreads();
    int wid = tid >> 6, lane = tid & 63;
#pragma unroll
    for (int it = 0; it < 8; ++it) {
        int tl = it * 4 + wid;
        float v[6];
        float s = 0.f;
#pragma unroll
        for (int i = 0; i < 6; ++i) { v[i] = t[(lane + 64 * i) * 33 + tl]; s += v[i]; }
#pragma unroll
        for (int o = 32; o; o >>= 1) s += __shfl_xor(s, o, 64);
        float mu = s * (1.f / DIM);
        float s2 = 0.f;
#pragma unroll
        for (int i = 0; i < 6; ++i) { float d = v[i] - mu; s2 += d * d; }
#pragma unroll
        for (int o = 32; o; o >>= 1) s2 += __shfl_xor(s2, o, 64);
        float r = rsqrtf(s2 * (1.f / DIM) + 1e-6f);
        size_t tok = (size_t)b * NTOK + n0 + tl;
#pragma unroll
        for (int i = 0; i < 6; ++i) {
            int c = lane + 64 * i;
            hOut[tok * DIM + c] = v[i];
            y[tok * DIM + c] = __float2bfloat16((v[i] - mu) * r * g[c] + bta[c]);
        }
    }
}

// ---------------------------------------------------------------------------
// V transpose with key-permutation: qkv bf16 [tok][1152] (V cols 768+h*48+d)
// -> VT [b*8+h][48][2048], where within each 128-key chunk the stored
// position p holds key k(p) = (p&7)*16 + (p>>3). This matches the MFMA
// C-layout of the S tile so attention's P-store is contiguous.
// Grid (NTOK/128, BATCH*NHEAD), 256 threads.
// ---------------------------------------------------------------------------
__global__ __launch_bounds__(256) void vtile(const u16* __restrict__ qkv,
                                             unsigned int* __restrict__ vt32) {
    __shared__ u16 t[128 * 49];
    int k0 = blockIdx.x * 128;
    int bh = blockIdx.y;
    int b = bh >> 3, h = bh & 7;
    int tid = threadIdx.x;
    const u16* src = qkv + (size_t)(b * NTOK + k0) * 1152 + 768 + h * 48;
    // load 128 keys x 48 dims (768 uint4), unpack to LDS [key][dim]
#pragma unroll
    for (int idx = tid; idx < 768; idx += 256) {
        int r = idx / 6, c = idx % 6;
        uint4 v = *(const uint4*)(src + (size_t)r * 1152 + c * 8);
        u16* dst = &t[r * 49 + c * 8];
        dst[0] = (u16)(v.x & 0xffff); dst[1] = (u16)(v.x >> 16);
        dst[2] = (u16)(v.y & 0xffff); dst[3] = (u16)(v.y >> 16);
        dst[4] = (u16)(v.z & 0xffff); dst[5] = (u16)(v.z >> 16);
        dst[6] = (u16)(v.w & 0xffff); dst[7] = (u16)(v.w >> 16);
    }
    __syncthreads();
    // write out in permuted order, packed as u32 (positions p=2*pp, 2*pp+1)
    unsigned int* outb = vt32 + (((size_t)bh * 48) * 2048 + k0) / 2;
#pragma unroll
    for (int idx = tid; idx < 3072; idx += 256) {
        int d = idx >> 6, pp = idx & 63;
        int k1 = (pp & 3) * 32 + (pp >> 2);      // key for pos p=2*pp
        unsigned int lo = t[k1 * 49 + d];
        unsigned int hi = t[(k1 + 16) * 49 + d]; // key for pos p=2*pp+1
        outb[(size_t)d * 1024 + pp] = lo | (hi << 16);
    }
}

// ---------------------------------------------------------------------------
// LayerNorm (LN2): one wave per token, 4 tokens/block. f32 in, bf16 out.
// ---------------------------------------------------------------------------
__global__ __launch_bounds__(256) void ln_kernel(const float* __restrict__ x,
                                                 const float* __restrict__ g,
                                                 const float* __restrict__ bta,
                                                 __hip_bfloat16* __restrict__ y) {
    int wid = threadIdx.x >> 6, lane = threadIdx.x & 63;
    int tok = blockIdx.x * 4 + wid;
    const float* xr = x + (size_t)tok * DIM;
    float v[6];
    float s = 0.f;
#pragma unroll
    for (int i = 0; i < 6; ++i) { v[i] = xr[lane + 64 * i]; s += v[i]; }
#pragma unroll
    for (int o = 32; o; o >>= 1) s += __shfl_xor(s, o, 64);
    float mu = s * (1.f / DIM);
    float s2 = 0.f;
#pragma unroll
    for (int i = 0; i < 6; ++i) { float d = v[i] - mu; s2 += d * d; }
#pragma unroll
    for (int o = 32; o; o >>= 1) s2 += __shfl_xor(s2, o, 64);
    float r = rsqrtf(s2 * (1.f / DIM) + 1e-6f);
    __hip_bfloat16* yr = y + (size_t)tok * DIM;
#pragma unroll
    for (int i = 0; i < 6; ++i) {
        int c = lane + 64 * i;
        yr[c] = __float2bfloat16((v[i] - mu) * r * g[c] + bta[c]);
    }
}

// ---------------------------------------------------------------------------
// 64x64x32 bf16 MFMA GEMM (round-6 known good): C = epi(A @ BT^T + bias) (+res)
// TRANSOUT: write f32 out[b][c][n] transposed via LDS tile (N must be 384).
// ---------------------------------------------------------------------------
template<bool GELU, bool BF16OUT, bool TRANSOUT>
__global__ __launch_bounds__(256) void gemm_mfma(
    const __hip_bfloat16* __restrict__ A,    // [M,K]
    const __hip_bfloat16* __restrict__ BT,   // [N,K]
    const float* __restrict__ bias,
    const float* __restrict__ res,
    void* __restrict__ Cout,
    int M, int N, int K) {
    __shared__ __align__(16) u16 As[64 * 32];
    __shared__ __align__(16) u16 Bs[64 * 32];
    int bm = blockIdx.y * 64, bn = blockIdx.x * 64;
    int tid = threadIdx.x;
    int w = tid >> 6, l = tid & 63;
    int m0 = (w >> 1) * 32, n0 = (w & 1) * 32;
    int lm = l & 15, ksel = l >> 4;

    int row = tid >> 2, c16 = tid & 3;
    const __hip_bfloat16* ga = A  + (size_t)(bm + row) * K + c16 * 8;
    const __hip_bfloat16* gb = BT + (size_t)(bn + row) * K + c16 * 8;
    u16* la = &As[tid * 8];
    u16* lb = &Bs[tid * 8];

    f32x4 acc[2][2] = {};
    for (int k0 = 0; k0 < K; k0 += 32) {
        load_lds16(ga + k0, la);
        load_lds16(gb + k0, lb);
        __syncthreads();
        bf16x8 af0 = *(const bf16x8*)&As[(m0 +      lm) * 32 + ksel * 8];
        bf16x8 af1 = *(const bf16x8*)&As[(m0 + 16 + lm) * 32 + ksel * 8];
        bf16x8 bf0 = *(const bf16x8*)&Bs[(n0 +      lm) * 32 + ksel * 8];
        bf16x8 bf1 = *(const bf16x8*)&Bs[(n0 + 16 + lm) * 32 + ksel * 8];
        acc[0][0] = __builtin_amdgcn_mfma_f32_16x16x32_bf16(af0, bf0, acc[0][0], 0, 0, 0);
        acc[0][1] = __builtin_amdgcn_mfma_f32_16x16x32_bf16(af0, bf1, acc[0][1], 0, 0, 0);
        acc[1][0] = __builtin_amdgcn_mfma_f32_16x16x32_bf16(af1, bf0, acc[1][0], 0, 0, 0);
        acc[1][1] = __builtin_amdgcn_mfma_f32_16x16x32_bf16(af1, bf1, acc[1][1], 0, 0, 0);
        __syncthreads();
    }

    if constexpr (TRANSOUT) {
        __shared__ float ct[64 * 65];
#pragma unroll
        for (int i = 0; i < 2; ++i)
#pragma unroll
            for (int j = 0; j < 2; ++j)
#pragma unroll
                for (int r = 0; r < 4; ++r) {
                    int ml = m0 + i * 16 + ksel * 4 + r;
                    int cl = n0 + j * 16 + lm;
                    float v = acc[i][j][r];
                    if (bias) v += bias[bn + cl];
                    if (res)  v += res[(size_t)(bm + ml) * N + bn + cl];
                    ct[ml * 65 + cl] = v;
                }
        __syncthreads();
        int bb = bm >> 11, nb = bm & (NTOK - 1);
        float* outp = (float*)Cout + (size_t)bb * DIM * NTOK + nb;
#pragma unroll
        for (int cl = w; cl < 64; cl += 4)
            outp[(size_t)(bn + cl) * NTOK + l] = ct[l * 65 + cl];
    } else {
#pragma unroll
        for (int i = 0; i < 2; ++i)
#pragma unroll
            for (int j = 0; j < 2; ++j)
#pragma unroll
                for (int r = 0; r < 4; ++r) {
                    int rg = bm + m0 + i * 16 + ksel * 4 + r;
                    int cg = bn + n0 + j * 16 + lm;
                    float v = acc[i][j][r];
                    if (bias) v += bias[cg];
                    if (GELU) v = 0.5f * v * (1.f + erff(v * 0.7071067811865475f));
                    if (res)  v += res[(size_t)rg * N + cg];
                    if (BF16OUT)
                        ((__hip_bfloat16*)Cout)[(size_t)rg * N + cg] = __float2bfloat16(v);
                    else
                        ((float*)Cout)[(size_t)rg * N + cg] = v;
                }
    }
}

// ---------------------------------------------------------------------------
// bf16 MFMA flash attention, 128-key tiles, one-pass softmax, key-permuted
// P/V (see vtile): P-store is 4x ds_write_b128 per tile (was 32 scalar).
// Grid (NTOK/64, NHEAD, BATCH), 256 threads = 4 waves; wave w owns q rows
// w*16..w*16+15.
// ---------------------------------------------------------------------------
#define ATK 128
#define PSTR 136   // 128 stored positions + 8 pad; rows 16B-aligned
__global__ __launch_bounds__(256) void attn_mfma(
    const u16* __restrict__ qkv,             // bf16 [TOKS][1152]
    const u16* __restrict__ vt,              // bf16 [16][48][2048] (permuted keys)
    __hip_bfloat16* __restrict__ outp) {     // bf16 [TOKS][DIM]
    __shared__ __align__(16) u16 Qs[64 * 72];
    __shared__ __align__(16) u16 Ks[128 * 72];
    __shared__ __align__(16) u16 Vs[48 * PSTR];
    __shared__ __align__(16) u16 Ps[64 * PSTR];
    const int q0 = blockIdx.x * 64;
    const int h = blockIdx.y, b = blockIdx.z;
    const int tid = threadIdx.x;
    const int w = tid >> 6, l = tid & 63, lm = l & 15, quad = l >> 4;

    for (int idx = tid; idx < 128; idx += 256) {
        int r = idx >> 1, c = idx & 1;
        *(uint4*)&Qs[r * 72 + 48 + c * 8] = uint4{0, 0, 0, 0};
    }
    {
        int r = tid >> 1, c = tid & 1;
        *(uint4*)&Ks[r * 72 + 48 + c * 8] = uint4{0, 0, 0, 0};
    }
    const u16* qbase = qkv + (size_t)(b * NTOK + q0) * 1152 + h * 48;
    for (int idx = tid; idx < 384; idx += 256) {
        int r = idx / 6, c = idx % 6;
        *(uint4*)&Qs[r * 72 + c * 8] = *(const uint4*)(qbase + (size_t)r * 1152 + c * 8);
    }
    __syncthreads();

    bf16x8 aq0 = *(const bf16x8*)&Qs[(w * 16 + lm) * 72 +  0 + quad * 8];
    bf16x8 aq1 = *(const bf16x8*)&Qs[(w * 16 + lm) * 72 + 32 + quad * 8];

    float l_i[4] = {0.f, 0.f, 0.f, 0.f};
    f32x4 o_acc[3] = {};

    const u16* kbase = qkv + (size_t)(b * NTOK) * 1152 + 384 + h * 48;
    const u16* vbase = vt + (size_t)(b * NHEAD + h) * 48 * 2048;
    const float sc2 = 0.14433756729740643f * 1.4426950408889634f;  // scale*log2e

    for (int kt = 0; kt < NTOK / ATK; ++kt) {
        __syncthreads();
        // stage K: 128 rows x 48 (768 uint4)
#pragma unroll
        for (int idx = tid; idx < 768; idx += 256) {
            int r = idx / 6, c = idx % 6;
            *(uint4*)&Ks[r * 72 + c * 8] =
                *(const uint4*)(kbase + (size_t)(kt * ATK + r) * 1152 + c * 8);
        }
        // stage V (permuted key order): 48 dims x 128 positions (768 uint4)
#pragma unroll
        for (int idx = tid; idx < 768; idx += 256) {
            int d = idx >> 4, c = idx & 15;
            *(uint4*)&Vs[d * PSTR + c * 8] =
                *(const uint4*)(vbase + (size_t)d * 2048 + kt * ATK + c * 8);
        }
        __syncthreads();

        // S = Q K^T : 8 key-subtiles of 16
        f32x4 s[8];
#pragma unroll
        for (int nt = 0; nt < 8; ++nt) {
            bf16x8 kf0 = *(const bf16x8*)&Ks[(nt * 16 + lm) * 72 +  0 + quad * 8];
            bf16x8 kf1 = *(const bf16x8*)&Ks[(nt * 16 + lm) * 72 + 32 + quad * 8];
            f32x4 t = {};
            t = __builtin_amdgcn_mfma_f32_16x16x32_bf16(aq0, kf0, t, 0, 0, 0);
            t = __builtin_amdgcn_mfma_f32_16x16x32_bf16(aq1, kf1, t, 0, 0, 0);
            s[nt] = t;
        }

        // P = exp2(S*sc2); thread's 8 values land contiguously at pos lm*8
        // (stored position p = lm*8+nt <-> key nt*16+lm, matching vt's perm)
#pragma unroll
        for (int r = 0; r < 4; ++r) {
            u16 pr[8];
#pragma unroll
            for (int nt = 0; nt < 8; ++nt) {
                float p = exp2f(s[nt][r] * sc2);
                l_i[r] += p;
                bfu cv; cv.h = __float2bfloat16(p);
                pr[nt] = cv.u;
            }
            *(uint4*)&Ps[(w * 16 + quad * 4 + r) * PSTR + lm * 8] = *(const uint4*)pr;
        }

        // O += P V (stored-position order matches between Ps and Vs)
#pragma unroll
        for (int ks = 0; ks < 4; ++ks) {
            bf16x8 pf = *(const bf16x8*)&Ps[(w * 16 + lm) * PSTR + ks * 32 + quad * 8];
#pragma unroll
            for (int nt = 0; nt < 3; ++nt) {
                bf16x8 vf = *(const bf16x8*)&Vs[(nt * 16 + lm) * PSTR + ks * 32 + quad * 8];
                o_acc[nt] = __builtin_amdgcn_mfma_f32_16x16x32_bf16(pf, vf, o_acc[nt], 0, 0, 0);
            }
        }
    }

#pragma unroll
    for (int r = 0; r < 4; ++r) {
        float lsum = l_i[r];
#pragma unroll
        for (int o = 8; o; o >>= 1) lsum += __shfl_xor(lsum, o, 64);
        float inv = 1.f / lsum;
#pragma unroll
        for (int nt = 0; nt < 3; ++nt)
            outp[(size_t)(b * NTOK + q0 + w * 16 + quad * 4 + r) * DIM + h * 48 + nt * 16 + lm]
                = __float2bfloat16(o_acc[nt][r] * inv);
    }
}

// ---------------------------------------------------------------------------
extern "C" void kernel_launch(void* const* d_in, const int* in_sizes, int n_in,
                              void* d_out, int out_size, void* d_ws, size_t ws_size,
                              hipStream_t stream) {
    const float* x    = (const float*)d_in[0];
    const float* g1   = (const float*)d_in[1];
    const float* b1   = (const float*)d_in[2];
    const float* Wqkv = (const float*)d_in[3];
    const float* Wo   = (const float*)d_in[4];
    const float* bo   = (const float*)d_in[5];
    const float* g2   = (const float*)d_in[6];
    const float* b2   = (const float*)d_in[7];
    const float* W1   = (const float*)d_in[8];
    const float* b1m  = (const float*)d_in[9];
    const float* W2   = (const float*)d_in[10];
    const float* b2m  = (const float*)d_in[11];
    float* out = (float*)d_out;

    char* p = (char*)d_ws;
    float* bufH = (float*)p;                       p += (size_t)TOKS * DIM * 4;      // f32 [4096,384]
    char* qkvp = p;
    __hip_bfloat16* bufQKVb = (__hip_bfloat16*)p;  p += (size_t)TOKS * 3 * DIM * 2;  // bf16 [4096,1152]
    __hip_bfloat16* bufVT   = (__hip_bfloat16*)p;  p += (size_t)TOKS * DIM * 2;      // bf16 [16,48,2048]
    __hip_bfloat16* bufNb   = (__hip_bfloat16*)p;  p += (size_t)TOKS * DIM * 2;      // bf16 [4096,384]
    __hip_bfloat16* bufAb   = (__hip_bfloat16*)p;  p += (size_t)TOKS * DIM * 2;      // bf16 [4096,384]
    __hip_bfloat16* WqkvT   = (__hip_bfloat16*)p;  p += (size_t)3 * DIM * DIM * 2;   // [1152,384]
    __hip_bfloat16* WoT     = (__hip_bfloat16*)p;  p += (size_t)DIM * DIM * 2;       // [384,384]
    __hip_bfloat16* W1T     = (__hip_bfloat16*)p;  p += (size_t)HIDDEN * DIM * 2;    // [1536,384]
    __hip_bfloat16* W2T     = (__hip_bfloat16*)p;  p += (size_t)DIM * HIDDEN * 2;    // [384,1536]
    __hip_bfloat16* bufHIDb = (__hip_bfloat16*)qkvp;  // bf16 [4096,1536] overlays QKV+VT

    // 0. all weight casts/transposes (one dispatch)
    wtrans_all<<<1728, 256, 0, stream>>>(Wqkv, Wo, W1, W2, WqkvT, WoT, W1T, W2T);
    // 1. fused transpose + LN1
    tln<<<dim3(NTOK / 32, BATCH), 256, 0, stream>>>(x, g1, b1, bufH, bufNb);
    // 2. QKV projection -> bf16
    gemm_mfma<false, true, false><<<dim3(3 * DIM / 64, TOKS / 64), 256, 0, stream>>>(
        bufNb, WqkvT, nullptr, nullptr, bufQKVb, TOKS, 3 * DIM, DIM);
    // 3. V transpose (permuted key order)
    vtile<<<dim3(NTOK / 128, BATCH * NHEAD), 256, 0, stream>>>(
        (const u16*)bufQKVb, (unsigned int*)bufVT);
    // 4. MFMA flash attention -> bf16
    attn_mfma<<<dim3(NTOK / 64, NHEAD, BATCH), 256, 0, stream>>>(
        (const u16*)bufQKVb, (const u16*)bufVT, bufAb);
    // 5. output projection + bias + residual -> f32 bufH (in place)
    gemm_mfma<false, false, false><<<dim3(DIM / 64, TOKS / 64), 256, 0, stream>>>(
        bufAb, WoT, bo, bufH, bufH, TOKS, DIM, DIM);
    // 6. LN2 -> bf16
    ln_kernel<<<TOKS / 4, 256, 0, stream>>>(bufH, g2, b2, bufNb);
    // 7. MLP up + GELU -> bf16 hidden
    gemm_mfma<true, true, false><<<dim3(HIDDEN / 64, TOKS / 64), 256, 0, stream>>>(
        bufNb, W1T, b1m, nullptr, bufHIDb, TOKS, HIDDEN, DIM);
    // 8. MLP down + bias + residual -> out (transposed write, f32)
    gemm_mfma<false, false, true><<<dim3(DIM / 64, TOKS / 64), 256, 0, stream>>>(
        bufHIDb, W2T, b2m, bufH, out, TOKS, DIM, HIDDEN);
}

// Round 11
// 197.832 us; speedup vs baseline: 1.4703x; 1.1293x over previous
//
#include <hip/hip_runtime.h>
#include <hip/hip_bf16.h>
#include <math.h>

#define DIM    384
#define NHEAD  8
#define HDIM   48
#define NTOK   2048              // tokens per batch (8*16*16)
#define BATCH  2
#define TOKS   (BATCH * NTOK)    // 4096
#define HIDDEN 1536

typedef __bf16 bf16x8 __attribute__((ext_vector_type(8)));
typedef float  f32x4  __attribute__((ext_vector_type(4)));
typedef unsigned short u16;

union bfu { __hip_bfloat16 h; u16 u; };

__device__ __forceinline__ void load_lds16(const void* g, void* l) {
    __builtin_amdgcn_global_load_lds(
        (const __attribute__((address_space(1))) void*)g,
        (__attribute__((address_space(3))) void*)l, 16, 0, 0);
}

// ---------------------------------------------------------------------------
// All four weight cast+transposes in ONE dispatch.
// in f32 [R][C] -> out bf16 [C][R]; block ranges select the matrix.
// ---------------------------------------------------------------------------
__global__ __launch_bounds__(256) void wtrans_all(
    const float* __restrict__ Wqkv, const float* __restrict__ Wo,
    const float* __restrict__ W1,   const float* __restrict__ W2,
    __hip_bfloat16* __restrict__ WqkvT, __hip_bfloat16* __restrict__ WoT,
    __hip_bfloat16* __restrict__ W1T,   __hip_bfloat16* __restrict__ W2T) {
    __shared__ float t[32][33];
    int id = blockIdx.x;
    const float* src; __hip_bfloat16* dst; int R, C;
    if (id < 432)       { src = Wqkv; dst = WqkvT; R = 384;  C = 1152; }
    else if (id < 576)  { id -= 432;  src = Wo;    dst = WoT;  R = 384;  C = 384; }
    else if (id < 1152) { id -= 576;  src = W1;    dst = W1T;  R = 384;  C = 1536; }
    else                { id -= 1152; src = W2;    dst = W2T;  R = 1536; C = 384; }
    int tc = C / 32;
    int i0 = (id / tc) * 32, j0 = (id % tc) * 32;
    int tx = threadIdx.x & 31, ty = threadIdx.x >> 5;
#pragma unroll
    for (int k = 0; k < 32; k += 8)
        t[ty + k][tx] = src[(size_t)(i0 + ty + k) * C + j0 + tx];
    __syncthreads();
#pragma unroll
    for (int k = 0; k < 32; k += 8)
        dst[(size_t)(j0 + ty + k) * R + i0 + tx] = __float2bfloat16(t[tx][ty + k]);
}

// ---------------------------------------------------------------------------
// Fused input transpose + LN1.
// ---------------------------------------------------------------------------
__global__ __launch_bounds__(256) void tln(const float* __restrict__ x,
                                           const float* __restrict__ g,
                                           const float* __restrict__ bta,
                                           float* __restrict__ hOut,
                                           __hip_bfloat16* __restrict__ y) {
    __shared__ float t[384 * 33];
    int n0 = blockIdx.x * 32, b = blockIdx.y;
    const float* xb = x + (size_t)b * DIM * NTOK;
    int tid = threadIdx.x;
    for (int idx = tid; idx < 384 * 32; idx += 256) {
        int c = idx >> 5, n = idx & 31;
        t[c * 33 + n] = xb[(size_t)c * NTOK + n0 + n];
    }
    __syncthreads();
    int wid = tid >> 6, lane = tid & 63;
#pragma unroll
    for (int it = 0; it < 8; ++it) {
        int tl = it * 4 + wid;
        float v[6];
        float s = 0.f;
#pragma unroll
        for (int i = 0; i < 6; ++i) { v[i] = t[(lane + 64 * i) * 33 + tl]; s += v[i]; }
#pragma unroll
        for (int o = 32; o; o >>= 1) s += __shfl_xor(s, o, 64);
        float mu = s * (1.f / DIM);
        float s2 = 0.f;
#pragma unroll
        for (int i = 0; i < 6; ++i) { float d = v[i] - mu; s2 += d * d; }
#pragma unroll
        for (int o = 32; o; o >>= 1) s2 += __shfl_xor(s2, o, 64);
        float r = rsqrtf(s2 * (1.f / DIM) + 1e-6f);
        size_t tok = (size_t)b * NTOK + n0 + tl;
#pragma unroll
        for (int i = 0; i < 6; ++i) {
            int c = lane + 64 * i;
            hOut[tok * DIM + c] = v[i];
            y[tok * DIM + c] = __float2bfloat16((v[i] - mu) * r * g[c] + bta[c]);
        }
    }
}

// ---------------------------------------------------------------------------
// V transpose with key-permutation: qkv bf16 [tok][1152] (V cols 768+h*48+d)
// -> VT [b*8+h][48][2048]. Within each 128-key chunk, stored position p holds
// key k(p) = ((p>>6)*4 + (p&3))*16 + ((p>>2)&15)  (kh-major halves so each
// key-half wave's positions are contiguous).
// Grid (NTOK/128, BATCH*NHEAD), 256 threads.
// ---------------------------------------------------------------------------
__global__ __launch_bounds__(256) void vtile(const u16* __restrict__ qkv,
                                             unsigned int* __restrict__ vt32) {
    __shared__ u16 t[128 * 49];
    int k0 = blockIdx.x * 128;
    int bh = blockIdx.y;
    int b = bh >> 3, h = bh & 7;
    int tid = threadIdx.x;
    const u16* src = qkv + (size_t)(b * NTOK + k0) * 1152 + 768 + h * 48;
#pragma unroll
    for (int idx = tid; idx < 768; idx += 256) {
        int r = idx / 6, c = idx % 6;
        uint4 v = *(const uint4*)(src + (size_t)r * 1152 + c * 8);
        u16* dst = &t[r * 49 + c * 8];
        dst[0] = (u16)(v.x & 0xffff); dst[1] = (u16)(v.x >> 16);
        dst[2] = (u16)(v.y & 0xffff); dst[3] = (u16)(v.y >> 16);
        dst[4] = (u16)(v.z & 0xffff); dst[5] = (u16)(v.z >> 16);
        dst[6] = (u16)(v.w & 0xffff); dst[7] = (u16)(v.w >> 16);
    }
    __syncthreads();
    // positions p=2*pp (lo) and 2*pp+1 (hi = lo key + 16) packed as u32
    unsigned int* outb = vt32 + (((size_t)bh * 48) * 2048 + k0) / 2;
#pragma unroll
    for (int idx = tid; idx < 3072; idx += 256) {
        int d = idx >> 6, pp = idx & 63;
        int k1 = (pp >> 5) * 64 + (pp & 1) * 32 + ((pp >> 1) & 15);
        unsigned int lo = t[k1 * 49 + d];
        unsigned int hi = t[(k1 + 16) * 49 + d];
        outb[(size_t)d * 1024 + pp] = lo | (hi << 16);
    }
}

// ---------------------------------------------------------------------------
// LayerNorm (LN2): one wave per token, 4 tokens/block. f32 in, bf16 out.
// ---------------------------------------------------------------------------
__global__ __launch_bounds__(256) void ln_kernel(const float* __restrict__ x,
                                                 const float* __restrict__ g,
                                                 const float* __restrict__ bta,
                                                 __hip_bfloat16* __restrict__ y) {
    int wid = threadIdx.x >> 6, lane = threadIdx.x & 63;
    int tok = blockIdx.x * 4 + wid;
    const float* xr = x + (size_t)tok * DIM;
    float v[6];
    float s = 0.f;
#pragma unroll
    for (int i = 0; i < 6; ++i) { v[i] = xr[lane + 64 * i]; s += v[i]; }
#pragma unroll
    for (int o = 32; o; o >>= 1) s += __shfl_xor(s, o, 64);
    float mu = s * (1.f / DIM);
    float s2 = 0.f;
#pragma unroll
    for (int i = 0; i < 6; ++i) { float d = v[i] - mu; s2 += d * d; }
#pragma unroll
    for (int o = 32; o; o >>= 1) s2 += __shfl_xor(s2, o, 64);
    float r = rsqrtf(s2 * (1.f / DIM) + 1e-6f);
    __hip_bfloat16* yr = y + (size_t)tok * DIM;
#pragma unroll
    for (int i = 0; i < 6; ++i) {
        int c = lane + 64 * i;
        yr[c] = __float2bfloat16((v[i] - mu) * r * g[c] + bta[c]);
    }
}

// ---------------------------------------------------------------------------
// 64x64 bf16 MFMA GEMM, BK=64 (two stride-32 sub-blocks -> half the barriers
// of the BK=32 version, same proven frag layout / staging contiguity).
// TRANSOUT: write f32 out[b][c][n] transposed via LDS tile (N must be 384).
// ---------------------------------------------------------------------------
template<bool GELU, bool BF16OUT, bool TRANSOUT>
__global__ __launch_bounds__(256) void gemm_mfma(
    const __hip_bfloat16* __restrict__ A,    // [M,K]
    const __hip_bfloat16* __restrict__ BT,   // [N,K]
    const float* __restrict__ bias,
    const float* __restrict__ res,
    void* __restrict__ Cout,
    int M, int N, int K) {
    __shared__ __align__(16) u16 As[2][64 * 32];
    __shared__ __align__(16) u16 Bs[2][64 * 32];
    int bm = blockIdx.y * 64, bn = blockIdx.x * 64;
    int tid = threadIdx.x;
    int w = tid >> 6, l = tid & 63;
    int m0 = (w >> 1) * 32, n0 = (w & 1) * 32;
    int lm = l & 15, ksel = l >> 4;

    int row = tid >> 2, c16 = tid & 3;
    const __hip_bfloat16* ga = A  + (size_t)(bm + row) * K + c16 * 8;
    const __hip_bfloat16* gb = BT + (size_t)(bn + row) * K + c16 * 8;

    f32x4 acc[2][2] = {};
    for (int k0 = 0; k0 < K; k0 += 64) {
        load_lds16(ga + k0,      &As[0][tid * 8]);
        load_lds16(ga + k0 + 32, &As[1][tid * 8]);
        load_lds16(gb + k0,      &Bs[0][tid * 8]);
        load_lds16(gb + k0 + 32, &Bs[1][tid * 8]);
        __syncthreads();
#pragma unroll
        for (int kk = 0; kk < 2; ++kk) {
            bf16x8 af0 = *(const bf16x8*)&As[kk][(m0 +      lm) * 32 + ksel * 8];
            bf16x8 af1 = *(const bf16x8*)&As[kk][(m0 + 16 + lm) * 32 + ksel * 8];
            bf16x8 bf0 = *(const bf16x8*)&Bs[kk][(n0 +      lm) * 32 + ksel * 8];
            bf16x8 bf1 = *(const bf16x8*)&Bs[kk][(n0 + 16 + lm) * 32 + ksel * 8];
            acc[0][0] = __builtin_amdgcn_mfma_f32_16x16x32_bf16(af0, bf0, acc[0][0], 0, 0, 0);
            acc[0][1] = __builtin_amdgcn_mfma_f32_16x16x32_bf16(af0, bf1, acc[0][1], 0, 0, 0);
            acc[1][0] = __builtin_amdgcn_mfma_f32_16x16x32_bf16(af1, bf0, acc[1][0], 0, 0, 0);
            acc[1][1] = __builtin_amdgcn_mfma_f32_16x16x32_bf16(af1, bf1, acc[1][1], 0, 0, 0);
        }
        __syncthreads();
    }

    if constexpr (TRANSOUT) {
        __shared__ float ct[64 * 65];
#pragma unroll
        for (int i = 0; i < 2; ++i)
#pragma unroll
            for (int j = 0; j < 2; ++j)
#pragma unroll
                for (int r = 0; r < 4; ++r) {
                    int ml = m0 + i * 16 + ksel * 4 + r;
                    int cl = n0 + j * 16 + lm;
                    float v = acc[i][j][r];
                    if (bias) v += bias[bn + cl];
                    if (res)  v += res[(size_t)(bm + ml) * N + bn + cl];
                    ct[ml * 65 + cl] = v;
                }
        __syncthreads();
        int bb = bm >> 11, nb = bm & (NTOK - 1);
        float* outp = (float*)Cout + (size_t)bb * DIM * NTOK + nb;
#pragma unroll
        for (int cl = w; cl < 64; cl += 4)
            outp[(size_t)(bn + cl) * NTOK + l] = ct[l * 65 + cl];
    } else {
#pragma unroll
        for (int i = 0; i < 2; ++i)
#pragma unroll
            for (int j = 0; j < 2; ++j)
#pragma unroll
                for (int r = 0; r < 4; ++r) {
                    int rg = bm + m0 + i * 16 + ksel * 4 + r;
                    int cg = bn + n0 + j * 16 + lm;
                    float v = acc[i][j][r];
                    if (bias) v += bias[cg];
                    if (GELU) v = 0.5f * v * (1.f + erff(v * 0.7071067811865475f));
                    if (res)  v += res[(size_t)rg * N + cg];
                    if (BF16OUT)
                        ((__hip_bfloat16*)Cout)[(size_t)rg * N + cg] = __float2bfloat16(v);
                    else
                        ((float*)Cout)[(size_t)rg * N + cg] = v;
                }
    }
}

// ---------------------------------------------------------------------------
// bf16 MFMA flash attention, 128-key tiles, one-pass softmax, 512 threads =
// 8 waves: wave w -> q-chunk qc=w>>1 (16 rows), key-half kh=w&1 (64 keys).
// Per-wave work halves vs the 4-wave version; occupancy doubles (16 waves/CU).
// P/V permutation p = kh*64 + lm*4 + nt' keeps P-store/PV wave-private.
// End: LDS reduction (reusing Ks) merges kh=0/1 partial O and l.
// ---------------------------------------------------------------------------
#define ATK 128
#define PSTR 136   // row stride in u16; rows 16B-aligned
__global__ __launch_bounds__(512) void attn_mfma(
    const u16* __restrict__ qkv,             // bf16 [TOKS][1152]
    const u16* __restrict__ vt,              // bf16 [16][48][2048] (permuted keys)
    __hip_bfloat16* __restrict__ outp) {     // bf16 [TOKS][DIM]
    __shared__ __align__(16) u16 Qs[64 * 72];
    __shared__ __align__(16) u16 Ks[128 * 72];
    __shared__ __align__(16) u16 Vs[48 * PSTR];
    __shared__ __align__(16) u16 Ps[64 * PSTR];
    const int q0 = blockIdx.x * 64;
    const int h = blockIdx.y, b = blockIdx.z;
    const int tid = threadIdx.x;
    const int w = tid >> 6, l = tid & 63, lm = l & 15, quad = l >> 4;
    const int qc = w >> 1, kh = w & 1;

    // zero k-pads (cols 48..63)
    for (int idx = tid; idx < 128; idx += 512) {
        int r = idx >> 1, c = idx & 1;
        *(uint4*)&Qs[r * 72 + 48 + c * 8] = uint4{0, 0, 0, 0};
    }
    for (int idx = tid; idx < 256; idx += 512) {
        int r = idx >> 1, c = idx & 1;
        *(uint4*)&Ks[r * 72 + 48 + c * 8] = uint4{0, 0, 0, 0};
    }
    // stage Q tile (64 rows x 48)
    const u16* qbase = qkv + (size_t)(b * NTOK + q0) * 1152 + h * 48;
    for (int idx = tid; idx < 384; idx += 512) {
        int r = idx / 6, c = idx % 6;
        *(uint4*)&Qs[r * 72 + c * 8] = *(const uint4*)(qbase + (size_t)r * 1152 + c * 8);
    }
    __syncthreads();

    bf16x8 aq0 = *(const bf16x8*)&Qs[(qc * 16 + lm) * 72 +  0 + quad * 8];
    bf16x8 aq1 = *(const bf16x8*)&Qs[(qc * 16 + lm) * 72 + 32 + quad * 8];

    float l_i[4] = {0.f, 0.f, 0.f, 0.f};
    f32x4 o_acc[3] = {};

    const u16* kbase = qkv + (size_t)(b * NTOK) * 1152 + 384 + h * 48;
    const u16* vbase = vt + (size_t)(b * NHEAD + h) * 48 * 2048;
    const float sc2 = 0.14433756729740643f * 1.4426950408889634f;  // scale*log2e

    for (int kt = 0; kt < NTOK / ATK; ++kt) {
        __syncthreads();
        // stage K: 128 rows x 48 (768 uint4)
#pragma unroll
        for (int idx = tid; idx < 768; idx += 512) {
            int r = idx / 6, c = idx % 6;
            *(uint4*)&Ks[r * 72 + c * 8] =
                *(const uint4*)(kbase + (size_t)(kt * ATK + r) * 1152 + c * 8);
        }
        // stage V (permuted key order): 48 dims x 128 positions (768 uint4)
#pragma unroll
        for (int idx = tid; idx < 768; idx += 512) {
            int d = idx >> 4, c = idx & 15;
            *(uint4*)&Vs[d * PSTR + c * 8] =
                *(const uint4*)(vbase + (size_t)d * 2048 + kt * ATK + c * 8);
        }
        __syncthreads();

        // S = Q K^T for this wave's 4 key-subtiles
        f32x4 s[4];
#pragma unroll
        for (int ntp = 0; ntp < 4; ++ntp) {
            int nt = kh * 4 + ntp;
            bf16x8 kf0 = *(const bf16x8*)&Ks[(nt * 16 + lm) * 72 +  0 + quad * 8];
            bf16x8 kf1 = *(const bf16x8*)&Ks[(nt * 16 + lm) * 72 + 32 + quad * 8];
            f32x4 t = {};
            t = __builtin_amdgcn_mfma_f32_16x16x32_bf16(aq0, kf0, t, 0, 0, 0);
            t = __builtin_amdgcn_mfma_f32_16x16x32_bf16(aq1, kf1, t, 0, 0, 0);
            s[ntp] = t;
        }

        // P = exp2(S*sc2); store 4 contiguous u16 at position kh*64 + lm*4
#pragma unroll
        for (int r = 0; r < 4; ++r) {
            u16 pr[4];
#pragma unroll
            for (int ntp = 0; ntp < 4; ++ntp) {
                float p = exp2f(s[ntp][r] * sc2);
                l_i[r] += p;
                bfu cv; cv.h = __float2bfloat16(p);
                pr[ntp] = cv.u;
            }
            *(uint2*)&Ps[(qc * 16 + quad * 4 + r) * PSTR + kh * 64 + lm * 4] =
                *(const uint2*)pr;
        }

        // O += P V over this wave's 64 stored positions (wave-private rows)
#pragma unroll
        for (int ksp = 0; ksp < 2; ++ksp) {
            int ks = kh * 2 + ksp;
            bf16x8 pf = *(const bf16x8*)&Ps[(qc * 16 + lm) * PSTR + ks * 32 + quad * 8];
#pragma unroll
            for (int nt = 0; nt < 3; ++nt) {
                bf16x8 vf = *(const bf16x8*)&Vs[(nt * 16 + lm) * PSTR + ks * 32 + quad * 8];
                o_acc[nt] = __builtin_amdgcn_mfma_f32_16x16x32_bf16(pf, vf, o_acc[nt], 0, 0, 0);
            }
        }
    }

    // merge kh=0 / kh=1 partials via LDS (reuse Ks as f32 scratch)
    __syncthreads();
    float* red = (float*)Ks;
    if (kh == 1) {
        f32x4* base = (f32x4*)&red[(qc * 64 + l) * 16];
        base[0] = o_acc[0]; base[1] = o_acc[1]; base[2] = o_acc[2];
        f32x4 lv; lv[0] = l_i[0]; lv[1] = l_i[1]; lv[2] = l_i[2]; lv[3] = l_i[3];
        base[3] = lv;
    }
    __syncthreads();
    if (kh == 0) {
        f32x4* base = (f32x4*)&red[(qc * 64 + l) * 16];
        o_acc[0] += base[0]; o_acc[1] += base[1]; o_acc[2] += base[2];
        f32x4 lv = base[3];
#pragma unroll
        for (int r = 0; r < 4; ++r) {
            float lsum = l_i[r] + lv[r];
#pragma unroll
            for (int o = 8; o; o >>= 1) lsum += __shfl_xor(lsum, o, 64);
            float inv = 1.f / lsum;
#pragma unroll
            for (int nt = 0; nt < 3; ++nt)
                outp[(size_t)(b * NTOK + q0 + qc * 16 + quad * 4 + r) * DIM
                     + h * 48 + nt * 16 + lm]
                    = __float2bfloat16(o_acc[nt][r] * inv);
        }
    }
}

// ---------------------------------------------------------------------------
extern "C" void kernel_launch(void* const* d_in, const int* in_sizes, int n_in,
                              void* d_out, int out_size, void* d_ws, size_t ws_size,
                              hipStream_t stream) {
    const float* x    = (const float*)d_in[0];
    const float* g1   = (const float*)d_in[1];
    const float* b1   = (const float*)d_in[2];
    const float* Wqkv = (const float*)d_in[3];
    const float* Wo   = (const float*)d_in[4];
    const float* bo   = (const float*)d_in[5];
    const float* g2   = (const float*)d_in[6];
    const float* b2   = (const float*)d_in[7];
    const float* W1   = (const float*)d_in[8];
    const float* b1m  = (const float*)d_in[9];
    const float* W2   = (const float*)d_in[10];
    const float* b2m  = (const float*)d_in[11];
    float* out = (float*)d_out;

    char* p = (char*)d_ws;
    float* bufH = (float*)p;                       p += (size_t)TOKS * DIM * 4;      // f32 [4096,384]
    char* qkvp = p;
    __hip_bfloat16* bufQKVb = (__hip_bfloat16*)p;  p += (size_t)TOKS * 3 * DIM * 2;  // bf16 [4096,1152]
    __hip_bfloat16* bufVT   = (__hip_bfloat16*)p;  p += (size_t)TOKS * DIM * 2;      // bf16 [16,48,2048]
    __hip_bfloat16* bufNb   = (__hip_bfloat16*)p;  p += (size_t)TOKS * DIM * 2;      // bf16 [4096,384]
    __hip_bfloat16* bufAb   = (__hip_bfloat16*)p;  p += (size_t)TOKS * DIM * 2;      // bf16 [4096,384]
    __hip_bfloat16* WqkvT   = (__hip_bfloat16*)p;  p += (size_t)3 * DIM * DIM * 2;   // [1152,384]
    __hip_bfloat16* WoT     = (__hip_bfloat16*)p;  p += (size_t)DIM * DIM * 2;       // [384,384]
    __hip_bfloat16* W1T     = (__hip_bfloat16*)p;  p += (size_t)HIDDEN * DIM * 2;    // [1536,384]
    __hip_bfloat16* W2T     = (__hip_bfloat16*)p;  p += (size_t)DIM * HIDDEN * 2;    // [384,1536]
    __hip_bfloat16* bufHIDb = (__hip_bfloat16*)qkvp;  // bf16 [4096,1536] overlays QKV+VT

    // 0. all weight casts/transposes (one dispatch)
    wtrans_all<<<1728, 256, 0, stream>>>(Wqkv, Wo, W1, W2, WqkvT, WoT, W1T, W2T);
    // 1. fused transpose + LN1
    tln<<<dim3(NTOK / 32, BATCH), 256, 0, stream>>>(x, g1, b1, bufH, bufNb);
    // 2. QKV projection -> bf16
    gemm_mfma<false, true, false><<<dim3(3 * DIM / 64, TOKS / 64), 256, 0, stream>>>(
        bufNb, WqkvT, nullptr, nullptr, bufQKVb, TOKS, 3 * DIM, DIM);
    // 3. V transpose (permuted key order)
    vtile<<<dim3(NTOK / 128, BATCH * NHEAD), 256, 0, stream>>>(
        (const u16*)bufQKVb, (unsigned int*)bufVT);
    // 4. MFMA flash attention -> bf16 (512 threads)
    attn_mfma<<<dim3(NTOK / 64, NHEAD, BATCH), 512, 0, stream>>>(
        (const u16*)bufQKVb, (const u16*)bufVT, bufAb);
    // 5. output projection + bias + residual -> f32 bufH (in place)
    gemm_mfma<false, false, false><<<dim3(DIM / 64, TOKS / 64), 256, 0, stream>>>(
        bufAb, WoT, bo, bufH, bufH, TOKS, DIM, DIM);
    // 6. LN2 -> bf16
    ln_kernel<<<TOKS / 4, 256, 0, stream>>>(bufH, g2, b2, bufNb);
    // 7. MLP up + GELU -> bf16 hidden
    gemm_mfma<true, true, false><<<dim3(HIDDEN / 64, TOKS / 64), 256, 0, stream>>>(
        bufNb, W1T, b1m, nullptr, bufHIDb, TOKS, HIDDEN, DIM);
    // 8. MLP down + bias + residual -> out (transposed write, f32)
    gemm_mfma<false, false, true><<<dim3(DIM / 64, TOKS / 64), 256, 0, stream>>>(
        bufHIDb, W2T, b2m, bufH, out, TOKS, DIM, HIDDEN);
}

// Round 12
// 197.294 us; speedup vs baseline: 1.4743x; 1.0027x over previous
//
#include <hip/hip_runtime.h>
#include <hip/hip_bf16.h>
#include <math.h>

#define DIM    384
#define NHEAD  8
#define HDIM   48
#define NTOK   2048              // tokens per batch (8*16*16)
#define BATCH  2
#define TOKS   (BATCH * NTOK)    // 4096
#define HIDDEN 1536

typedef __bf16 bf16x8 __attribute__((ext_vector_type(8)));
typedef float  f32x4  __attribute__((ext_vector_type(4)));
typedef unsigned short u16;

union bfu { __hip_bfloat16 h; u16 u; };

__device__ __forceinline__ void load_lds16(const void* g, void* l) {
    __builtin_amdgcn_global_load_lds(
        (const __attribute__((address_space(1))) void*)g,
        (__attribute__((address_space(3))) void*)l, 16, 0, 0);
}

// ---------------------------------------------------------------------------
// prep: 4 weight cast+transposes (blocks 0..1727) + fused input transpose/LN1
// (blocks 1728..1855) in ONE dispatch.
// ---------------------------------------------------------------------------
__global__ __launch_bounds__(256) void prep(
    const float* __restrict__ Wqkv, const float* __restrict__ Wo,
    const float* __restrict__ W1,   const float* __restrict__ W2,
    __hip_bfloat16* __restrict__ WqkvT, __hip_bfloat16* __restrict__ WoT,
    __hip_bfloat16* __restrict__ W1T,   __hip_bfloat16* __restrict__ W2T,
    const float* __restrict__ x, const float* __restrict__ g,
    const float* __restrict__ bta,
    float* __restrict__ hOut, __hip_bfloat16* __restrict__ y) {
    __shared__ __align__(16) char smem[384 * 33 * 4];
    int id = blockIdx.x;
    int tid = threadIdx.x;
    if (id < 1728) {
        float (*t)[33] = (float(*)[33])smem;
        const float* src; __hip_bfloat16* dst; int R, C;
        if (id < 432)       { src = Wqkv; dst = WqkvT; R = 384;  C = 1152; }
        else if (id < 576)  { id -= 432;  src = Wo;    dst = WoT;  R = 384;  C = 384; }
        else if (id < 1152) { id -= 576;  src = W1;    dst = W1T;  R = 384;  C = 1536; }
        else                { id -= 1152; src = W2;    dst = W2T;  R = 1536; C = 384; }
        int tc = C / 32;
        int i0 = (id / tc) * 32, j0 = (id % tc) * 32;
        int tx = tid & 31, ty = tid >> 5;
#pragma unroll
        for (int k = 0; k < 32; k += 8)
            t[ty + k][tx] = src[(size_t)(i0 + ty + k) * C + j0 + tx];
        __syncthreads();
#pragma unroll
        for (int k = 0; k < 32; k += 8)
            dst[(size_t)(j0 + ty + k) * R + i0 + tx] = __float2bfloat16(t[tx][ty + k]);
    } else {
        float* t = (float*)smem;
        int id2 = id - 1728;
        int n0 = (id2 & 63) * 32, b = id2 >> 6;
        const float* xb = x + (size_t)b * DIM * NTOK;
        for (int idx = tid; idx < 384 * 32; idx += 256) {
            int c = idx >> 5, n = idx & 31;
            t[c * 33 + n] = xb[(size_t)c * NTOK + n0 + n];
        }
        __syncthreads();
        int wid = tid >> 6, lane = tid & 63;
#pragma unroll
        for (int it = 0; it < 8; ++it) {
            int tl = it * 4 + wid;
            float v[6];
            float s = 0.f;
#pragma unroll
            for (int i = 0; i < 6; ++i) { v[i] = t[(lane + 64 * i) * 33 + tl]; s += v[i]; }
#pragma unroll
            for (int o = 32; o; o >>= 1) s += __shfl_xor(s, o, 64);
            float mu = s * (1.f / DIM);
            float s2 = 0.f;
#pragma unroll
            for (int i = 0; i < 6; ++i) { float d = v[i] - mu; s2 += d * d; }
#pragma unroll
            for (int o = 32; o; o >>= 1) s2 += __shfl_xor(s2, o, 64);
            float r = rsqrtf(s2 * (1.f / DIM) + 1e-6f);
            size_t tok = (size_t)b * NTOK + n0 + tl;
#pragma unroll
            for (int i = 0; i < 6; ++i) {
                int c = lane + 64 * i;
                hOut[tok * DIM + c] = v[i];
                y[tok * DIM + c] = __float2bfloat16((v[i] - mu) * r * g[c] + bta[c]);
            }
        }
    }
}

// ---------------------------------------------------------------------------
// LayerNorm (LN2): one wave per token, 4 tokens/block. f32 in, bf16 out.
// ---------------------------------------------------------------------------
__global__ __launch_bounds__(256) void ln_kernel(const float* __restrict__ x,
                                                 const float* __restrict__ g,
                                                 const float* __restrict__ bta,
                                                 __hip_bfloat16* __restrict__ y) {
    int wid = threadIdx.x >> 6, lane = threadIdx.x & 63;
    int tok = blockIdx.x * 4 + wid;
    const float* xr = x + (size_t)tok * DIM;
    float v[6];
    float s = 0.f;
#pragma unroll
    for (int i = 0; i < 6; ++i) { v[i] = xr[lane + 64 * i]; s += v[i]; }
#pragma unroll
    for (int o = 32; o; o >>= 1) s += __shfl_xor(s, o, 64);
    float mu = s * (1.f / DIM);
    float s2 = 0.f;
#pragma unroll
    for (int i = 0; i < 6; ++i) { float d = v[i] - mu; s2 += d * d; }
#pragma unroll
    for (int o = 32; o; o >>= 1) s2 += __shfl_xor(s2, o, 64);
    float r = rsqrtf(s2 * (1.f / DIM) + 1e-6f);
    __hip_bfloat16* yr = y + (size_t)tok * DIM;
#pragma unroll
    for (int i = 0; i < 6; ++i) {
        int c = lane + 64 * i;
        yr[c] = __float2bfloat16((v[i] - mu) * r * g[c] + bta[c]);
    }
}

// ---------------------------------------------------------------------------
// 64x64 bf16 MFMA GEMM, BK=64 (two stride-32 sub-blocks).
// TRANSOUT: write f32 out[b][c][n] transposed via LDS tile (N must be 384).
// QKV: cols <768 -> bf16 C[M,1152]; cols >=768 (V) -> permuted VT directly.
// ---------------------------------------------------------------------------
template<bool GELU, bool BF16OUT, bool TRANSOUT, bool QKV>
__global__ __launch_bounds__(256) void gemm_mfma(
    const __hip_bfloat16* __restrict__ A,    // [M,K]
    const __hip_bfloat16* __restrict__ BT,   // [N,K]
    const float* __restrict__ bias,
    const float* __restrict__ res,
    void* __restrict__ Cout,
    int M, int N, int K,
    __hip_bfloat16* __restrict__ vtout) {
    __shared__ __align__(16) u16 As[2][64 * 32];
    __shared__ __align__(16) u16 Bs[2][64 * 32];
    int bm = blockIdx.y * 64, bn = blockIdx.x * 64;
    int tid = threadIdx.x;
    int w = tid >> 6, l = tid & 63;
    int m0 = (w >> 1) * 32, n0 = (w & 1) * 32;
    int lm = l & 15, ksel = l >> 4;

    int row = tid >> 2, c16 = tid & 3;
    const __hip_bfloat16* ga = A  + (size_t)(bm + row) * K + c16 * 8;
    const __hip_bfloat16* gb = BT + (size_t)(bn + row) * K + c16 * 8;

    f32x4 acc[2][2] = {};
    for (int k0 = 0; k0 < K; k0 += 64) {
        load_lds16(ga + k0,      &As[0][tid * 8]);
        load_lds16(ga + k0 + 32, &As[1][tid * 8]);
        load_lds16(gb + k0,      &Bs[0][tid * 8]);
        load_lds16(gb + k0 + 32, &Bs[1][tid * 8]);
        __syncthreads();
#pragma unroll
        for (int kk = 0; kk < 2; ++kk) {
            bf16x8 af0 = *(const bf16x8*)&As[kk][(m0 +      lm) * 32 + ksel * 8];
            bf16x8 af1 = *(const bf16x8*)&As[kk][(m0 + 16 + lm) * 32 + ksel * 8];
            bf16x8 bf0 = *(const bf16x8*)&Bs[kk][(n0 +      lm) * 32 + ksel * 8];
            bf16x8 bf1 = *(const bf16x8*)&Bs[kk][(n0 + 16 + lm) * 32 + ksel * 8];
            acc[0][0] = __builtin_amdgcn_mfma_f32_16x16x32_bf16(af0, bf0, acc[0][0], 0, 0, 0);
            acc[0][1] = __builtin_amdgcn_mfma_f32_16x16x32_bf16(af0, bf1, acc[0][1], 0, 0, 0);
            acc[1][0] = __builtin_amdgcn_mfma_f32_16x16x32_bf16(af1, bf0, acc[1][0], 0, 0, 0);
            acc[1][1] = __builtin_amdgcn_mfma_f32_16x16x32_bf16(af1, bf1, acc[1][1], 0, 0, 0);
        }
        __syncthreads();
    }

    if constexpr (TRANSOUT) {
        __shared__ float ct[64 * 65];
#pragma unroll
        for (int i = 0; i < 2; ++i)
#pragma unroll
            for (int j = 0; j < 2; ++j)
#pragma unroll
                for (int r = 0; r < 4; ++r) {
                    int ml = m0 + i * 16 + ksel * 4 + r;
                    int cl = n0 + j * 16 + lm;
                    float v = acc[i][j][r];
                    if (bias) v += bias[bn + cl];
                    if (res)  v += res[(size_t)(bm + ml) * N + bn + cl];
                    ct[ml * 65 + cl] = v;
                }
        __syncthreads();
        int bb = bm >> 11, nb = bm & (NTOK - 1);
        float* outp = (float*)Cout + (size_t)bb * DIM * NTOK + nb;
#pragma unroll
        for (int cl = w; cl < 64; cl += 4)
            outp[(size_t)(bn + cl) * NTOK + l] = ct[l * 65 + cl];
    } else {
#pragma unroll
        for (int i = 0; i < 2; ++i)
#pragma unroll
            for (int j = 0; j < 2; ++j)
#pragma unroll
                for (int r = 0; r < 4; ++r) {
                    int rg = bm + m0 + i * 16 + ksel * 4 + r;
                    int cg = bn + n0 + j * 16 + lm;
                    float v = acc[i][j][r];
                    if (bias) v += bias[cg];
                    if (GELU) v = 0.5f * v * (1.f + erff(v * 0.7071067811865475f));
                    if (res)  v += res[(size_t)rg * N + cg];
                    if constexpr (QKV) {
                        if (cg < 768) {
                            ((__hip_bfloat16*)Cout)[(size_t)rg * 1152 + cg] = __float2bfloat16(v);
                        } else {
                            int c = cg - 768, hh = c / 48, dd = c - hh * 48;
                            int bb = rg >> 11, n = rg & (NTOK - 1);
                            int kk = n & 127;
                            int pos = ((kk >> 6) << 6) + ((kk & 15) << 2) + ((kk >> 4) & 3);
                            vtout[((size_t)(bb * NHEAD + hh) * 48 + dd) * 2048
                                  + (n & ~127) + pos] = __float2bfloat16(v);
                        }
                    } else if constexpr (BF16OUT) {
                        ((__hip_bfloat16*)Cout)[(size_t)rg * N + cg] = __float2bfloat16(v);
                    } else {
                        ((float*)Cout)[(size_t)rg * N + cg] = v;
                    }
                }
    }
}

// ---------------------------------------------------------------------------
// bf16 MFMA flash attention, 128-key tiles, one-pass softmax, 512 threads =
// 8 waves: wave w -> q-chunk qc=w>>1 (16 rows), key-half kh=w&1 (64 keys).
// Ps OVERLAYS Qs (Q fragments live in registers after the prologue; two
// barriers separate the last Q read from the first P write). LDS 47.8 KB
// -> 3 blocks/CU; launch_bounds(512,6) caps VGPR so 24 waves/CU fit.
// ---------------------------------------------------------------------------
#define ATK 128
#define PSTR 136   // row stride in u16; rows 16B-aligned
__global__ __launch_bounds__(512, 6) void attn_mfma(
    const u16* __restrict__ qkv,             // bf16 [TOKS][1152] (Q,K valid)
    const u16* __restrict__ vt,              // bf16 [16][48][2048] (permuted keys)
    __hip_bfloat16* __restrict__ outp) {     // bf16 [TOKS][DIM]
    __shared__ __align__(16) u16 PQ[64 * PSTR];   // Qs (stride 72) then Ps
    __shared__ __align__(16) u16 Ks[128 * 72];
    __shared__ __align__(16) u16 Vs[48 * PSTR];
    const int q0 = blockIdx.x * 64;
    const int h = blockIdx.y, b = blockIdx.z;
    const int tid = threadIdx.x;
    const int w = tid >> 6, l = tid & 63, lm = l & 15, quad = l >> 4;
    const int qc = w >> 1, kh = w & 1;

    // zero Q k-pad (cols 48..63), stage Q tile (64 rows x 48) at stride 72
    for (int idx = tid; idx < 128; idx += 512) {
        int r = idx >> 1, c = idx & 1;
        *(uint4*)&PQ[r * 72 + 48 + c * 8] = uint4{0, 0, 0, 0};
    }
    for (int idx = tid; idx < 256; idx += 512) {
        int r = idx >> 1, c = idx & 1;
        *(uint4*)&Ks[r * 72 + 48 + c * 8] = uint4{0, 0, 0, 0};
    }
    const u16* qbase = qkv + (size_t)(b * NTOK + q0) * 1152 + h * 48;
    for (int idx = tid; idx < 384; idx += 512) {
        int r = idx / 6, c = idx % 6;
        *(uint4*)&PQ[r * 72 + c * 8] = *(const uint4*)(qbase + (size_t)r * 1152 + c * 8);
    }
    __syncthreads();

    bf16x8 aq0 = *(const bf16x8*)&PQ[(qc * 16 + lm) * 72 +  0 + quad * 8];
    bf16x8 aq1 = *(const bf16x8*)&PQ[(qc * 16 + lm) * 72 + 32 + quad * 8];

    float l_i[4] = {0.f, 0.f, 0.f, 0.f};
    f32x4 o_acc[3] = {};

    const u16* kbase = qkv + (size_t)(b * NTOK) * 1152 + 384 + h * 48;
    const u16* vbase = vt + (size_t)(b * NHEAD + h) * 48 * 2048;
    const float sc2 = 0.14433756729740643f * 1.4426950408889634f;  // scale*log2e

    for (int kt = 0; kt < NTOK / ATK; ++kt) {
        __syncthreads();   // all waves past Q-frag reads / prior-iter reads
        // stage K: 128 rows x 48 (768 uint4)
#pragma unroll
        for (int idx = tid; idx < 768; idx += 512) {
            int r = idx / 6, c = idx % 6;
            *(uint4*)&Ks[r * 72 + c * 8] =
                *(const uint4*)(kbase + (size_t)(kt * ATK + r) * 1152 + c * 8);
        }
        // stage V (permuted key order): 48 dims x 128 positions (768 uint4)
#pragma unroll
        for (int idx = tid; idx < 768; idx += 512) {
            int d = idx >> 4, c = idx & 15;
            *(uint4*)&Vs[d * PSTR + c * 8] =
                *(const uint4*)(vbase + (size_t)d * 2048 + kt * ATK + c * 8);
        }
        __syncthreads();

        // S = Q K^T for this wave's 4 key-subtiles
        f32x4 s[4];
#pragma unroll
        for (int ntp = 0; ntp < 4; ++ntp) {
            int nt = kh * 4 + ntp;
            bf16x8 kf0 = *(const bf16x8*)&Ks[(nt * 16 + lm) * 72 +  0 + quad * 8];
            bf16x8 kf1 = *(const bf16x8*)&Ks[(nt * 16 + lm) * 72 + 32 + quad * 8];
            f32x4 t = {};
            t = __builtin_amdgcn_mfma_f32_16x16x32_bf16(aq0, kf0, t, 0, 0, 0);
            t = __builtin_amdgcn_mfma_f32_16x16x32_bf16(aq1, kf1, t, 0, 0, 0);
            s[ntp] = t;
        }

        // P = exp2(S*sc2); store 4 contiguous u16 at position kh*64 + lm*4
#pragma unroll
        for (int r = 0; r < 4; ++r) {
            u16 pr[4];
#pragma unroll
            for (int ntp = 0; ntp < 4; ++ntp) {
                float p = exp2f(s[ntp][r] * sc2);
                l_i[r] += p;
                bfu cv; cv.h = __float2bfloat16(p);
                pr[ntp] = cv.u;
            }
            *(uint2*)&PQ[(qc * 16 + quad * 4 + r) * PSTR + kh * 64 + lm * 4] =
                *(const uint2*)pr;
        }

        // O += P V over this wave's 64 stored positions (wave-private rows)
#pragma unroll
        for (int ksp = 0; ksp < 2; ++ksp) {
            int ks = kh * 2 + ksp;
            bf16x8 pf = *(const bf16x8*)&PQ[(qc * 16 + lm) * PSTR + ks * 32 + quad * 8];
#pragma unroll
            for (int nt = 0; nt < 3; ++nt) {
                bf16x8 vf = *(const bf16x8*)&Vs[(nt * 16 + lm) * PSTR + ks * 32 + quad * 8];
                o_acc[nt] = __builtin_amdgcn_mfma_f32_16x16x32_bf16(pf, vf, o_acc[nt], 0, 0, 0);
            }
        }
    }

    // merge kh=0 / kh=1 partials via LDS (reuse Ks as f32 scratch)
    __syncthreads();
    float* red = (float*)Ks;
    if (kh == 1) {
        f32x4* base = (f32x4*)&red[(qc * 64 + l) * 16];
        base[0] = o_acc[0]; base[1] = o_acc[1]; base[2] = o_acc[2];
        f32x4 lv; lv[0] = l_i[0]; lv[1] = l_i[1]; lv[2] = l_i[2]; lv[3] = l_i[3];
        base[3] = lv;
    }
    __syncthreads();
    if (kh == 0) {
        f32x4* base = (f32x4*)&red[(qc * 64 + l) * 16];
        o_acc[0] += base[0]; o_acc[1] += base[1]; o_acc[2] += base[2];
        f32x4 lv = base[3];
#pragma unroll
        for (int r = 0; r < 4; ++r) {
            float lsum = l_i[r] + lv[r];
#pragma unroll
            for (int o = 8; o; o >>= 1) lsum += __shfl_xor(lsum, o, 64);
            float inv = 1.f / lsum;
#pragma unroll
            for (int nt = 0; nt < 3; ++nt)
                outp[(size_t)(b * NTOK + q0 + qc * 16 + quad * 4 + r) * DIM
                     + h * 48 + nt * 16 + lm]
                    = __float2bfloat16(o_acc[nt][r] * inv);
        }
    }
}

// ---------------------------------------------------------------------------
extern "C" void kernel_launch(void* const* d_in, const int* in_sizes, int n_in,
                              void* d_out, int out_size, void* d_ws, size_t ws_size,
                              hipStream_t stream) {
    const float* x    = (const float*)d_in[0];
    const float* g1   = (const float*)d_in[1];
    const float* b1   = (const float*)d_in[2];
    const float* Wqkv = (const float*)d_in[3];
    const float* Wo   = (const float*)d_in[4];
    const float* bo   = (const float*)d_in[5];
    const float* g2   = (const float*)d_in[6];
    const float* b2   = (const float*)d_in[7];
    const float* W1   = (const float*)d_in[8];
    const float* b1m  = (const float*)d_in[9];
    const float* W2   = (const float*)d_in[10];
    const float* b2m  = (const float*)d_in[11];
    float* out = (float*)d_out;

    char* p = (char*)d_ws;
    float* bufH = (float*)p;                       p += (size_t)TOKS * DIM * 4;      // f32 [4096,384]
    char* qkvp = p;
    __hip_bfloat16* bufQKVb = (__hip_bfloat16*)p;  p += (size_t)TOKS * 3 * DIM * 2;  // bf16 [4096,1152]
    __hip_bfloat16* bufVT   = (__hip_bfloat16*)p;  p += (size_t)TOKS * DIM * 2;      // bf16 [16,48,2048]
    __hip_bfloat16* bufNb   = (__hip_bfloat16*)p;  p += (size_t)TOKS * DIM * 2;      // bf16 [4096,384]
    __hip_bfloat16* bufAb   = (__hip_bfloat16*)p;  p += (size_t)TOKS * DIM * 2;      // bf16 [4096,384]
    __hip_bfloat16* WqkvT   = (__hip_bfloat16*)p;  p += (size_t)3 * DIM * DIM * 2;   // [1152,384]
    __hip_bfloat16* WoT     = (__hip_bfloat16*)p;  p += (size_t)DIM * DIM * 2;       // [384,384]
    __hip_bfloat16* W1T     = (__hip_bfloat16*)p;  p += (size_t)HIDDEN * DIM * 2;    // [1536,384]
    __hip_bfloat16* W2T     = (__hip_bfloat16*)p;  p += (size_t)DIM * HIDDEN * 2;    // [384,1536]
    __hip_bfloat16* bufHIDb = (__hip_bfloat16*)qkvp;  // bf16 [4096,1536] overlays QKV+VT

    // 0. weight transposes + input transpose/LN1 (one dispatch)
    prep<<<1728 + 128, 256, 0, stream>>>(Wqkv, Wo, W1, W2, WqkvT, WoT, W1T, W2T,
                                         x, g1, b1, bufH, bufNb);
    // 1. QKV projection: Q,K -> bufQKVb; V -> bufVT (permuted) directly
    gemm_mfma<false, true, false, true><<<dim3(3 * DIM / 64, TOKS / 64), 256, 0, stream>>>(
        bufNb, WqkvT, nullptr, nullptr, bufQKVb, TOKS, 3 * DIM, DIM, bufVT);
    // 2. MFMA flash attention -> bf16 (512 threads, 3 blocks/CU)
    attn_mfma<<<dim3(NTOK / 64, NHEAD, BATCH), 512, 0, stream>>>(
        (const u16*)bufQKVb, (const u16*)bufVT, bufAb);
    // 3. output projection + bias + residual -> f32 bufH (in place)
    gemm_mfma<false, false, false, false><<<dim3(DIM / 64, TOKS / 64), 256, 0, stream>>>(
        bufAb, WoT, bo, bufH, bufH, TOKS, DIM, DIM, nullptr);
    // 4. LN2 -> bf16
    ln_kernel<<<TOKS / 4, 256, 0, stream>>>(bufH, g2, b2, bufNb);
    // 5. MLP up + GELU -> bf16 hidden
    gemm_mfma<true, true, false, false><<<dim3(HIDDEN / 64, TOKS / 64), 256, 0, stream>>>(
        bufNb, W1T, b1m, nullptr, bufHIDb, TOKS, HIDDEN, DIM, nullptr);
    // 6. MLP down + bias + residual -> out (transposed write, f32)
    gemm_mfma<false, false, true, false><<<dim3(DIM / 64, TOKS / 64), 256, 0, stream>>>(
        bufHIDb, W2T, b2m, bufH, out, TOKS, DIM, HIDDEN, nullptr);
}